// Round 1
// baseline (626.758 us; speedup 1.0000x reference)
//
#include <hip/hip_runtime.h>
#include <math.h>

#define NN 8192
#define DD 512
#define CC 1000

__device__ __forceinline__ float waveRedSum(float v){
  #pragma unroll
  for(int o=32;o;o>>=1) v += __shfl_xor(v,o,64);
  return v;
}
__device__ __forceinline__ float waveRedMax(float v){
  #pragma unroll
  for(int o=32;o;o>>=1) v = fmaxf(v,__shfl_xor(v,o,64));
  return v;
}

// K1: p = softmax(logits, axis=1) + 1e-8. one block per row.
__global__ __launch_bounds__(256) void k_softmax(const float* __restrict__ logits,
                                                 float* __restrict__ p){
  __shared__ float sc[4];
  int row = blockIdx.x; int t = threadIdx.x;
  const float* lr = logits + (size_t)row*CC;
  float v[4]; float mx = -INFINITY;
  #pragma unroll
  for(int k=0;k<4;k++){ int c=t+256*k; v[k] = (c<CC)? lr[c] : -INFINITY; mx = fmaxf(mx, v[k]); }
  mx = waveRedMax(mx);
  if((t&63)==0) sc[t>>6]=mx;
  __syncthreads();
  mx = fmaxf(fmaxf(sc[0],sc[1]),fmaxf(sc[2],sc[3]));
  __syncthreads();
  float s=0.f;
  #pragma unroll
  for(int k=0;k<4;k++){ int c=t+256*k; if(c<CC){ v[k]=expf(v[k]-mx); s+=v[k]; } }
  s = waveRedSum(s);
  if((t&63)==0) sc[t>>6]=s;
  __syncthreads();
  s = sc[0]+sc[1]+sc[2]+sc[3];
  float inv = 1.0f/s;
  float* pr = p + (size_t)row*CC;
  #pragma unroll
  for(int k=0;k<4;k++){ int c=t+256*k; if(c<CC) pr[c] = v[k]*inv + 1e-8f; }
}

// K2: g[d] = sum_i F[i][d]. 64 blocks x 512 threads, 128 rows each, atomic.
__global__ __launch_bounds__(512) void k_colsum(const float* __restrict__ F,
                                                float* __restrict__ g){
  int d = threadIdx.x;
  size_t i0 = (size_t)blockIdx.x * 128;
  float s = 0.f;
  for(int i=0;i<128;i++) s += F[(i0+i)*DD + d];
  atomicAdd(&g[d], s);
}

// K3: T[d][c] += sum_{i in chunk} F[i][d]*P[i][c]. 128d x 128c tile, 8x8/thread,
// split-K over 16 chunks of 512 rows, fp32 atomics into T (zeroed beforehand).
__global__ __launch_bounds__(256) void k_tgemm(const float* __restrict__ F,
                                               const float* __restrict__ P,
                                               float* __restrict__ T){
  __shared__ float Fs[4][144];   // 128 floats + XOR-ish pad swizzle (2-way max)
  __shared__ float Ps[4][144];
  int c0 = blockIdx.x * 128;
  int d0 = blockIdx.y * 128;
  int i0 = blockIdx.z * 512;
  int t = threadIdx.x;
  int tx = t & 15, ty = t >> 4;
  float acc[8][8];
  #pragma unroll
  for(int a=0;a<8;a++)
    #pragma unroll
    for(int b=0;b<8;b++) acc[a][b]=0.f;

  for(int ib=0; ib<512; ib+=4){
    __syncthreads();
    #pragma unroll
    for(int q=0;q<2;q++){
      int ee = t + q*256;               // 0..511
      int rr = ee>>7, idx = ee&127;
      int sw = idx + ((idx>>5)<<2);     // pad 4 floats every 32
      Fs[rr][sw] = F[(size_t)(i0+ib+rr)*DD + d0 + idx];
      int c = c0 + idx;
      Ps[rr][sw] = (c<CC) ? P[(size_t)(i0+ib+rr)*CC + c] : 0.f;
    }
    __syncthreads();
    #pragma unroll
    for(int rr=0;rr<4;rr++){
      const float4* Fr = (const float4*)Fs[rr];
      const float4* Pr = (const float4*)Ps[rr];
      int jf0 = ty*2,  jf1 = ty*2+1;
      int jp0 = tx*2,  jp1 = tx*2+1;
      float4 f0 = Fr[jf0 + (jf0>>3)];
      float4 f1 = Fr[jf1 + (jf1>>3)];
      float4 q0 = Pr[jp0 + (jp0>>3)];
      float4 q1 = Pr[jp1 + (jp1>>3)];
      float fv[8] = {f0.x,f0.y,f0.z,f0.w,f1.x,f1.y,f1.z,f1.w};
      float pv[8] = {q0.x,q0.y,q0.z,q0.w,q1.x,q1.y,q1.z,q1.w};
      #pragma unroll
      for(int a=0;a<8;a++)
        #pragma unroll
        for(int b=0;b<8;b++) acc[a][b] += fv[a]*pv[b];
    }
  }
  #pragma unroll
  for(int a=0;a<8;a++){
    int d = d0 + ty*8 + a;
    #pragma unroll
    for(int b=0;b<8;b++){
      int c = c0 + tx*8 + b;
      if(c<CC) atomicAdd(&T[(size_t)d*CC + c], acc[a][b]);
    }
  }
}

// K5: for 16 rows/block: r_i = f_i.g - 1 ; M = F @ T ; ws=(M-p)/r ;
// partial KL = sum ws*log(ws/p) -> partials[block]
__global__ __launch_bounds__(256) void k_fused(const float* __restrict__ F,
                                               const float* __restrict__ T,
                                               const float* __restrict__ p,
                                               const float* __restrict__ g,
                                               float* __restrict__ partials){
  __shared__ float Fs[16][512];
  __shared__ float gs[512];
  __shared__ float invr[16];
  __shared__ float red[4];
  int t = threadIdx.x;
  int row0 = blockIdx.x * 16;
  for(int e=t; e<16*512; e+=256){
    int rr = e>>9, d = e&511;
    Fs[rr][d] = F[(size_t)(row0+rr)*DD + d];
  }
  gs[t]     = g[t];
  gs[t+256] = g[t+256];
  __syncthreads();

  int lane = t & 63, w = t >> 6;
  #pragma unroll
  for(int q=0;q<4;q++){
    int rr = w*4+q;
    float s=0.f;
    #pragma unroll
    for(int j=0;j<8;j++){ int d = lane + 64*j; s += Fs[rr][d]*gs[d]; }
    s = waveRedSum(s);
    if(lane==0) invr[rr] = 1.0f/(s - 1.0f);
  }
  __syncthreads();

  int c4 = t*4;
  bool cok = (c4 < CC);          // threads 0..249 hold valid columns
  float acc[16][4];
  #pragma unroll
  for(int rr=0;rr<16;rr++)
    #pragma unroll
    for(int k=0;k<4;k++) acc[rr][k]=0.f;

  for(int d0=0; d0<512; d0+=4){
    float4 tv[4];
    #pragma unroll
    for(int dd=0;dd<4;dd++){
      if(cok) tv[dd] = *(const float4*)&T[(size_t)(d0+dd)*CC + c4];
      else    tv[dd] = make_float4(0.f,0.f,0.f,0.f);
    }
    #pragma unroll
    for(int rr=0;rr<16;rr++){
      float4 fv = *(const float4*)&Fs[rr][d0];
      acc[rr][0] += fv.x*tv[0].x + fv.y*tv[1].x + fv.z*tv[2].x + fv.w*tv[3].x;
      acc[rr][1] += fv.x*tv[0].y + fv.y*tv[1].y + fv.z*tv[2].y + fv.w*tv[3].y;
      acc[rr][2] += fv.x*tv[0].z + fv.y*tv[1].z + fv.z*tv[2].z + fv.w*tv[3].z;
      acc[rr][3] += fv.x*tv[0].w + fv.y*tv[1].w + fv.z*tv[2].w + fv.w*tv[3].w;
    }
  }

  float kl = 0.f;
  if(cok){
    #pragma unroll
    for(int rr=0;rr<16;rr++){
      float4 pv = *(const float4*)&p[(size_t)(row0+rr)*CC + c4];
      float ir = invr[rr];
      float ws;
      ws = (acc[rr][0]-pv.x)*ir; kl += ws * logf(ws/pv.x);
      ws = (acc[rr][1]-pv.y)*ir; kl += ws * logf(ws/pv.y);
      ws = (acc[rr][2]-pv.z)*ir; kl += ws * logf(ws/pv.z);
      ws = (acc[rr][3]-pv.w)*ir; kl += ws * logf(ws/pv.w);
    }
  }
  kl = waveRedSum(kl);
  if(lane==0) red[w]=kl;
  __syncthreads();
  if(t==0) partials[blockIdx.x] = red[0]+red[1]+red[2]+red[3];
}

// K6: out = sum(partials)/N in double
__global__ __launch_bounds__(64) void k_finalize(const float* __restrict__ partials,
                                                 float* __restrict__ out){
  int l = threadIdx.x;
  double s = 0.0;
  for(int j=l; j<512; j+=64) s += (double)partials[j];
  #pragma unroll
  for(int o=32;o;o>>=1) s += __shfl_xor(s,o,64);
  if(l==0) out[0] = (float)(s / (double)NN);
}

extern "C" void kernel_launch(void* const* d_in, const int* in_sizes, int n_in,
                              void* d_out, int out_size, void* d_ws, size_t ws_size,
                              hipStream_t stream){
  const float* F = (const float*)d_in[0];   // features [N, D]
  const float* L = (const float*)d_in[1];   // logits   [N, C]
  float* out = (float*)d_out;
  float* ws  = (float*)d_ws;

  float* p        = ws;                              // N*C
  float* T        = p + (size_t)NN*CC;               // D*C
  float* g        = T + (size_t)DD*CC;               // D
  float* partials = g + DD;                          // 512

  // zero T and g (atomically accumulated every call)
  hipMemsetAsync(T, 0, ((size_t)DD*CC + DD)*sizeof(float), stream);

  hipLaunchKernelGGL(k_softmax, dim3(NN),       dim3(256), 0, stream, L, p);
  hipLaunchKernelGGL(k_colsum,  dim3(64),       dim3(512), 0, stream, F, g);
  hipLaunchKernelGGL(k_tgemm,   dim3(8,4,16),   dim3(256), 0, stream, F, p, T);
  hipLaunchKernelGGL(k_fused,   dim3(NN/16),    dim3(256), 0, stream, F, T, p, g, partials);
  hipLaunchKernelGGL(k_finalize,dim3(1),        dim3(64),  0, stream, partials, out);
}

// Round 2
// 117.281 us; speedup vs baseline: 5.3441x; 5.3441x over previous
//
#include <hip/hip_runtime.h>
#include <math.h>

#define NN 8192
#define DD 512
#define CC 1000
#define CP 1024   // padded C

typedef __attribute__((ext_vector_type(8))) short short8;     // bf16x8 MFMA frag
typedef __attribute__((ext_vector_type(4))) float f32x4;
typedef __attribute__((ext_vector_type(4))) unsigned short us4;
typedef __attribute__((ext_vector_type(8))) unsigned short us8;

__device__ __forceinline__ float bf2f(unsigned short u){
  union{unsigned int i; float f;} v; v.i = ((unsigned int)u)<<16; return v.f;
}
__device__ __forceinline__ unsigned short f2bf(float f){
  union{float f; unsigned int i;} v; v.f = f;
  unsigned int r = v.i + 0x7FFF + ((v.i>>16)&1);   // RNE
  return (unsigned short)(r>>16);
}
__device__ __forceinline__ float waveRedSum(float v){
  #pragma unroll
  for(int o=32;o;o>>=1) v += __shfl_xor(v,o,64);
  return v;
}
__device__ __forceinline__ float waveRedMax(float v){
  #pragma unroll
  for(int o=32;o;o>>=1) v = fmaxf(v,__shfl_xor(v,o,64));
  return v;
}
__device__ __forceinline__ void gload_lds16(const void* g, void* l){
  __builtin_amdgcn_global_load_lds((const __attribute__((address_space(1))) void*)g,
                                   (__attribute__((address_space(3))) void*)l, 16, 0, 0);
}

// ---- K1: F (fp32) -> FbT (bf16, [512][8192]) + fp32 colsum partials gpart[128][512]
__global__ __launch_bounds__(256) void k_castF(const float* __restrict__ F,
                                               unsigned short* __restrict__ FbT,
                                               float* __restrict__ gpart){
  __shared__ unsigned short lds[64*68];
  __shared__ float gq[16*64];
  int t = threadIdx.x;
  int i0 = blockIdx.x*64, d0 = blockIdx.y*64;
  int cx = t&15, ry = t>>4;
  float ca0=0.f,ca1=0.f,ca2=0.f,ca3=0.f;
  #pragma unroll
  for(int rr=0;rr<4;rr++){
    int row = rr*16 + ry;
    f32x4 fv = *(const f32x4*)&F[(size_t)(i0+row)*DD + d0 + cx*4];
    us4 u; u[0]=f2bf(fv[0]); u[1]=f2bf(fv[1]); u[2]=f2bf(fv[2]); u[3]=f2bf(fv[3]);
    *(us4*)&lds[row*68 + cx*4] = u;
    ca0+=fv[0]; ca1+=fv[1]; ca2+=fv[2]; ca3+=fv[3];
  }
  {
    f32x4 cv; cv[0]=ca0; cv[1]=ca1; cv[2]=ca2; cv[3]=ca3;
    *(f32x4*)&gq[ry*64 + cx*4] = cv;
  }
  __syncthreads();
  // transposed write: FbT[d][i]
  #pragma unroll
  for(int rr=0;rr<4;rr++){
    int d = rr*16 + ry;
    us4 u;
    #pragma unroll
    for(int q=0;q<4;q++) u[q] = lds[(cx*4+q)*68 + d];
    *(us4*)&FbT[(size_t)(d0+d)*NN + i0 + cx*4] = u;
  }
  __syncthreads();
  if(t<64){
    float s=0.f;
    #pragma unroll
    for(int j=0;j<16;j++) s += gq[j*64+t];
    gpart[blockIdx.x*DD + d0 + t] = s;
  }
}

// ---- K2: g[d] = sum over 128 partial groups (deterministic)
__global__ __launch_bounds__(512) void k_gred(const float* __restrict__ gpart,
                                              float* __restrict__ g){
  int t = threadIdx.x;
  float s=0.f;
  for(int j=0;j<128;j++) s += gpart[j*DD + t];
  g[t] = s;
}

// ---- K3: invr[i] = 1/(f_i . g - 1)   (fp32, one wave per row)
__global__ __launch_bounds__(256) void k_invr(const float* __restrict__ F,
                                              const float* __restrict__ g,
                                              float* __restrict__ invr){
  int t = threadIdx.x, l = t&63, w = t>>6;
  int row = blockIdx.x*4 + w;
  const float* fr = F + (size_t)row*DD + l*8;
  f32x4 a = *(const f32x4*)fr, b = *(const f32x4*)(fr+4);
  f32x4 ga = *(const f32x4*)&g[l*8], gb = *(const f32x4*)&g[l*8+4];
  float s = a[0]*ga[0]+a[1]*ga[1]+a[2]*ga[2]+a[3]*ga[3]
          + b[0]*gb[0]+b[1]*gb[1]+b[2]*gb[2]+b[3]*gb[3];
  s = waveRedSum(s);
  if(l==0) invr[row] = 1.0f/(s - 1.0f);
}

// ---- K4: softmax + transpose: logits [8192][1000] -> PbT bf16 [1024][8192]
__global__ __launch_bounds__(256) void k_softmaxT(const float* __restrict__ L,
                                                  unsigned short* __restrict__ PbT){
  __shared__ unsigned short lt[CP*16];   // [c][rr] 32KB
  int t = threadIdx.x, l = t&63, w = t>>6;
  int i0 = blockIdx.x*16;
  #pragma unroll
  for(int q=0;q<4;q++){
    int row = i0 + w*4 + q;
    const float* lr = L + (size_t)row*CC;
    float v[16]; float mx = -1e30f;
    #pragma unroll
    for(int k=0;k<16;k++){ int c = l + 64*k; v[k] = (c<CC)? lr[c] : -1e30f; mx = fmaxf(mx,v[k]); }
    mx = waveRedMax(mx);
    float s = 0.f;
    #pragma unroll
    for(int k=0;k<16;k++){ v[k] = expf(v[k]-mx); s += v[k]; }
    s = waveRedSum(s);
    float inv = 1.0f/s;
    #pragma unroll
    for(int k=0;k<16;k++){
      int c = l + 64*k;
      float p = v[k]*inv + 1e-8f;
      lt[c*16 + (w*4+q)] = (c<CC)? f2bf(p) : (unsigned short)0;
    }
  }
  __syncthreads();
  #pragma unroll
  for(int k=0;k<4;k++){
    int c = t + 256*k;
    us8 a = *(const us8*)&lt[c*16];
    us8 b = *(const us8*)&lt[c*16+8];
    *(us8*)&PbT[(size_t)c*NN + i0] = a;
    *(us8*)&PbT[(size_t)c*NN + i0 + 8] = b;
  }
}

// ---- K5: GEMM1: Tt[c][d] += sum_k PbT[c][k]*FbT[d][k], split-K=16, fp32 atomics
__global__ __launch_bounds__(256,2) void k_gemm1(const unsigned short* __restrict__ A,  // PbT [1024][8192]
                                                 const unsigned short* __restrict__ B,  // FbT [512][8192]
                                                 float* __restrict__ Tt){
  __shared__ unsigned short Al[128*64];
  __shared__ unsigned short Bl[128*64];
  int t = threadIdx.x, l = t&63, w = t>>6;
  int m0 = blockIdx.x*128, n0 = blockIdx.y*128;
  int k0 = blockIdx.z*512;
  int wm = w>>1, wn = w&1;
  f32x4 acc[4][4] = {};
  int srow = w*32 + (l>>3);
  int scl  = (l&7) ^ (srow&7);                 // pre-swizzled source chunk
  const unsigned short* Ab = A + (size_t)(m0 + srow)*NN + k0 + scl*8;
  const unsigned short* Bb = B + (size_t)(n0 + srow)*NN + k0 + scl*8;
  unsigned short* AlB = Al + (w*32)*64;
  unsigned short* BlB = Bl + (w*32)*64;

  for(int kt=0; kt<512; kt+=64){
    __syncthreads();
    #pragma unroll
    for(int q=0;q<4;q++){
      gload_lds16(Ab + (size_t)q*8*NN + kt, AlB + q*8*64);
      gload_lds16(Bb + (size_t)q*8*NN + kt, BlB + q*8*64);
    }
    asm volatile("s_waitcnt vmcnt(0)" ::: "memory");
    __syncthreads();
    #pragma unroll
    for(int ks=0;ks<2;ks++){
      short8 af[4], bf[4];
      #pragma unroll
      for(int mi=0;mi<4;mi++){
        int r = wm*64 + mi*16 + (l&15);
        int ch = ((ks<<2) + (l>>4)) ^ (r&7);
        af[mi] = *(const short8*)&Al[r*64 + ch*8];
      }
      #pragma unroll
      for(int ni=0;ni<4;ni++){
        int r = wn*64 + ni*16 + (l&15);
        int ch = ((ks<<2) + (l>>4)) ^ (r&7);
        bf[ni] = *(const short8*)&Bl[r*64 + ch*8];
      }
      #pragma unroll
      for(int mi=0;mi<4;mi++)
        #pragma unroll
        for(int ni=0;ni<4;ni++)
          acc[mi][ni] = __builtin_amdgcn_mfma_f32_16x16x32_bf16(af[mi], bf[ni], acc[mi][ni], 0,0,0);
    }
  }
  int rbase = (l>>4)*4;
  #pragma unroll
  for(int mi=0;mi<4;mi++){
    int c = m0 + wm*64 + mi*16 + rbase;
    #pragma unroll
    for(int ni=0;ni<4;ni++){
      int d = n0 + wn*64 + ni*16 + (l&15);
      #pragma unroll
      for(int j=0;j<4;j++)
        atomicAdd(&Tt[(size_t)(c+j)*DD + d], acc[mi][ni][j]);
    }
  }
}

// ---- K6: Tt fp32 -> Ttb bf16
__global__ __launch_bounds__(256) void k_castT(const float* __restrict__ Tt,
                                               unsigned short* __restrict__ Ttb){
  int i = (blockIdx.x*256 + threadIdx.x)*4;
  f32x4 v = *(const f32x4*)&Tt[i];
  us4 u; u[0]=f2bf(v[0]); u[1]=f2bf(v[1]); u[2]=f2bf(v[2]); u[3]=f2bf(v[3]);
  *(us4*)&Ttb[i] = u;
}

// ---- K7: GEMM2: M[i][c] = sum_d F[i][d]*Ttb[c][d]; fused KL epilogue
__global__ __launch_bounds__(256,2) void k_gemm2(const float* __restrict__ F,
                                                 const unsigned short* __restrict__ Bt,   // Ttb [1024][512]
                                                 const unsigned short* __restrict__ PbT,  // [1024][8192]
                                                 const float* __restrict__ invr,
                                                 float* __restrict__ partials){
  __shared__ unsigned short Al[128*64];
  __shared__ unsigned short Bl[128*64];
  __shared__ float red[4];
  int t = threadIdx.x, l = t&63, w = t>>6;
  int m0 = blockIdx.x*128, n0 = blockIdx.y*128;
  int wm = w>>1, wn = w&1;
  f32x4 acc[4][4] = {};
  int srow = w*32 + (l>>3);
  int scl  = (l&7) ^ (srow&7);
  const unsigned short* Bb = Bt + (size_t)(n0 + srow)*DD + scl*8;
  unsigned short* BlB = Bl + (w*32)*64;
  int ary = t>>4, acx = t&15;

  for(int kt=0; kt<512; kt+=64){
    __syncthreads();
    #pragma unroll
    for(int q=0;q<4;q++)
      gload_lds16(Bb + (size_t)q*8*DD + kt, BlB + q*8*64);
    // A staged from fp32 F with convert + swizzled ds_write
    #pragma unroll
    for(int rr=0;rr<8;rr++){
      int row = rr*16 + ary;
      f32x4 fv = *(const f32x4*)&F[(size_t)(m0+row)*DD + kt + acx*4];
      us4 u; u[0]=f2bf(fv[0]); u[1]=f2bf(fv[1]); u[2]=f2bf(fv[2]); u[3]=f2bf(fv[3]);
      int chS = (acx>>1) ^ (row&7);
      *(us4*)&Al[row*64 + chS*8 + (acx&1)*4] = u;
    }
    asm volatile("s_waitcnt vmcnt(0)" ::: "memory");
    __syncthreads();
    #pragma unroll
    for(int ks=0;ks<2;ks++){
      short8 af[4], bf[4];
      #pragma unroll
      for(int mi=0;mi<4;mi++){
        int r = wm*64 + mi*16 + (l&15);
        int ch = ((ks<<2) + (l>>4)) ^ (r&7);
        af[mi] = *(const short8*)&Al[r*64 + ch*8];
      }
      #pragma unroll
      for(int ni=0;ni<4;ni++){
        int r = wn*64 + ni*16 + (l&15);
        int ch = ((ks<<2) + (l>>4)) ^ (r&7);
        bf[ni] = *(const short8*)&Bl[r*64 + ch*8];
      }
      #pragma unroll
      for(int mi=0;mi<4;mi++)
        #pragma unroll
        for(int ni=0;ni<4;ni++)
          acc[mi][ni] = __builtin_amdgcn_mfma_f32_16x16x32_bf16(af[mi], bf[ni], acc[mi][ni], 0,0,0);
    }
  }
  // KL epilogue
  float kl = 0.f;
  int rbase = (l>>4)*4;
  #pragma unroll
  for(int mi=0;mi<4;mi++){
    int i_base = m0 + wm*64 + mi*16 + rbase;
    f32x4 ir4 = *(const f32x4*)&invr[i_base];
    #pragma unroll
    for(int ni=0;ni<4;ni++){
      int c = n0 + wn*64 + ni*16 + (l&15);
      if(c < CC){
        us4 p4 = *(const us4*)&PbT[(size_t)c*NN + i_base];
        #pragma unroll
        for(int j=0;j<4;j++){
          float p = bf2f(p4[j]);
          float ws = (acc[mi][ni][j] - p) * ir4[j];
          kl += ws * logf(ws/p);
        }
      }
    }
  }
  kl = waveRedSum(kl);
  if(l==0) red[w]=kl;
  __syncthreads();
  if(t==0) partials[blockIdx.y*64 + blockIdx.x] = red[0]+red[1]+red[2]+red[3];
}

// ---- K8: finalize
__global__ __launch_bounds__(64) void k_finalize(const float* __restrict__ partials,
                                                 float* __restrict__ out){
  int l = threadIdx.x;
  double s = 0.0;
  for(int j=l; j<512; j+=64) s += (double)partials[j];
  #pragma unroll
  for(int o=32;o;o>>=1) s += __shfl_xor(s,o,64);
  if(l==0) out[0] = (float)(s / (double)NN);
}

extern "C" void kernel_launch(void* const* d_in, const int* in_sizes, int n_in,
                              void* d_out, int out_size, void* d_ws, size_t ws_size,
                              hipStream_t stream){
  const float* F = (const float*)d_in[0];   // [8192][512]
  const float* L = (const float*)d_in[1];   // [8192][1000]
  float* out = (float*)d_out;

  unsigned char* w8 = (unsigned char*)d_ws;
  unsigned short* FbT = (unsigned short*)w8;                 // 512*8192*2   = 8 MB
  unsigned short* PbT = (unsigned short*)(w8 + 8388608);     // 1024*8192*2  = 16 MB
  float* Tt           = (float*)(w8 + 8388608 + 16777216);   // 1024*512*4   = 2 MB
  unsigned short* Ttb = (unsigned short*)(w8 + 27262976);    // 1024*512*2   = 1 MB
  float* gpart        = (float*)(w8 + 28311552);             // 128*512*4    = 256 KB
  float* g            = (float*)(w8 + 28573696);             // 512*4
  float* invr         = (float*)(w8 + 28575744);             // 8192*4
  float* partials     = (float*)(w8 + 28608512);             // 512*4

  hipMemsetAsync(Tt, 0, (size_t)CP*DD*sizeof(float), stream);

  hipLaunchKernelGGL(k_castF,    dim3(128,8),  dim3(256), 0, stream, F, FbT, gpart);
  hipLaunchKernelGGL(k_gred,     dim3(1),      dim3(512), 0, stream, gpart, g);
  hipLaunchKernelGGL(k_invr,     dim3(2048),   dim3(256), 0, stream, F, g, invr);
  hipLaunchKernelGGL(k_softmaxT, dim3(512),    dim3(256), 0, stream, L, PbT);
  hipLaunchKernelGGL(k_gemm1,    dim3(8,4,16), dim3(256), 0, stream, PbT, FbT, Tt);
  hipLaunchKernelGGL(k_castT,    dim3(512),    dim3(256), 0, stream, Tt, Ttb);
  hipLaunchKernelGGL(k_gemm2,    dim3(64,8),   dim3(256), 0, stream, F, Ttb, PbT, invr, partials);
  hipLaunchKernelGGL(k_finalize, dim3(1),      dim3(64),  0, stream, partials, out);
}

// Round 3
// 112.870 us; speedup vs baseline: 5.5529x; 1.0391x over previous
//
#include <hip/hip_runtime.h>
#include <math.h>

#define NN 8192
#define DD 512
#define CC 1000
#define CP 1024   // padded C

typedef __attribute__((ext_vector_type(8))) short short8;     // bf16x8 MFMA frag
typedef __attribute__((ext_vector_type(4))) float f32x4;
typedef __attribute__((ext_vector_type(2))) float f32x2;
typedef __attribute__((ext_vector_type(4))) unsigned short us4;
typedef __attribute__((ext_vector_type(8))) unsigned short us8;

__device__ __forceinline__ float bf2f(unsigned short u){
  union{unsigned int i; float f;} v; v.i = ((unsigned int)u)<<16; return v.f;
}
__device__ __forceinline__ unsigned short f2bf(float f){
  union{float f; unsigned int i;} v; v.f = f;
  unsigned int r = v.i + 0x7FFF + ((v.i>>16)&1);   // RNE
  return (unsigned short)(r>>16);
}
__device__ __forceinline__ float waveRedSum(float v){
  #pragma unroll
  for(int o=32;o;o>>=1) v += __shfl_xor(v,o,64);
  return v;
}
__device__ __forceinline__ float waveRedMax(float v){
  #pragma unroll
  for(int o=32;o;o>>=1) v = fmaxf(v,__shfl_xor(v,o,64));
  return v;
}
__device__ __forceinline__ void gload_lds16(const void* g, void* l){
  __builtin_amdgcn_global_load_lds((const __attribute__((address_space(1))) void*)g,
                                   (__attribute__((address_space(3))) void*)l, 16, 0, 0);
}

// ---- K1: F (fp32) -> FbT (bf16, [512][8192]) + fp32 colsum partials gpart[128][512]
//          + zero Tt (1024 blocks x 512 floats = CP*DD), replacing the slow rocclr fill
__global__ __launch_bounds__(256) void k_castF(const float* __restrict__ F,
                                               unsigned short* __restrict__ FbT,
                                               float* __restrict__ gpart,
                                               float* __restrict__ Tt){
  __shared__ unsigned short lds[64*68];
  __shared__ float gq[16*64];
  int t = threadIdx.x;
  // zero my slice of Tt (atomically accumulated by gemm1 every call)
  {
    size_t base = ((size_t)blockIdx.y*128 + blockIdx.x)*512 + (size_t)t*2;
    f32x2 z; z[0]=0.f; z[1]=0.f;
    *(f32x2*)&Tt[base] = z;
  }
  int i0 = blockIdx.x*64, d0 = blockIdx.y*64;
  int cx = t&15, ry = t>>4;
  float ca0=0.f,ca1=0.f,ca2=0.f,ca3=0.f;
  #pragma unroll
  for(int rr=0;rr<4;rr++){
    int row = rr*16 + ry;
    f32x4 fv = *(const f32x4*)&F[(size_t)(i0+row)*DD + d0 + cx*4];
    us4 u; u[0]=f2bf(fv[0]); u[1]=f2bf(fv[1]); u[2]=f2bf(fv[2]); u[3]=f2bf(fv[3]);
    *(us4*)&lds[row*68 + cx*4] = u;
    ca0+=fv[0]; ca1+=fv[1]; ca2+=fv[2]; ca3+=fv[3];
  }
  {
    f32x4 cv; cv[0]=ca0; cv[1]=ca1; cv[2]=ca2; cv[3]=ca3;
    *(f32x4*)&gq[ry*64 + cx*4] = cv;
  }
  __syncthreads();
  // transposed write: FbT[d][i]
  #pragma unroll
  for(int rr=0;rr<4;rr++){
    int d = rr*16 + ry;
    us4 u;
    #pragma unroll
    for(int q=0;q<4;q++) u[q] = lds[(cx*4+q)*68 + d];
    *(us4*)&FbT[(size_t)(d0+d)*NN + i0 + cx*4] = u;
  }
  __syncthreads();
  if(t<64){
    float s=0.f;
    #pragma unroll
    for(int j=0;j<16;j++) s += gq[j*64+t];
    gpart[blockIdx.x*DD + d0 + t] = s;
  }
}

// ---- K2: g[d] = sum over 128 partial groups (deterministic)
__global__ __launch_bounds__(512) void k_gred(const float* __restrict__ gpart,
                                              float* __restrict__ g){
  int t = threadIdx.x;
  float s=0.f;
  for(int j=0;j<128;j++) s += gpart[j*DD + t];
  g[t] = s;
}

// ---- K3: invr[i] = 1/(f_i . g - 1)   (fp32, one wave per row)
__global__ __launch_bounds__(256) void k_invr(const float* __restrict__ F,
                                              const float* __restrict__ g,
                                              float* __restrict__ invr){
  int t = threadIdx.x, l = t&63, w = t>>6;
  int row = blockIdx.x*4 + w;
  const float* fr = F + (size_t)row*DD + l*8;
  f32x4 a = *(const f32x4*)fr, b = *(const f32x4*)(fr+4);
  f32x4 ga = *(const f32x4*)&g[l*8], gb = *(const f32x4*)&g[l*8+4];
  float s = a[0]*ga[0]+a[1]*ga[1]+a[2]*ga[2]+a[3]*ga[3]
          + b[0]*gb[0]+b[1]*gb[1]+b[2]*gb[2]+b[3]*gb[3];
  s = waveRedSum(s);
  if(l==0) invr[row] = 1.0f/(s - 1.0f);
}

// ---- K4: softmax + transpose: logits [8192][1000] -> PbT bf16 [1024][8192]
__global__ __launch_bounds__(256) void k_softmaxT(const float* __restrict__ L,
                                                  unsigned short* __restrict__ PbT){
  __shared__ unsigned short lt[CP*16];   // [c][rr] 32KB
  int t = threadIdx.x, l = t&63, w = t>>6;
  int i0 = blockIdx.x*16;
  #pragma unroll
  for(int q=0;q<4;q++){
    int row = i0 + w*4 + q;
    const float* lr = L + (size_t)row*CC;
    float v[16]; float mx = -1e30f;
    #pragma unroll
    for(int k=0;k<16;k++){ int c = l + 64*k; v[k] = (c<CC)? lr[c] : -1e30f; mx = fmaxf(mx,v[k]); }
    mx = waveRedMax(mx);
    float s = 0.f;
    #pragma unroll
    for(int k=0;k<16;k++){ v[k] = expf(v[k]-mx); s += v[k]; }
    s = waveRedSum(s);
    float inv = 1.0f/s;
    #pragma unroll
    for(int k=0;k<16;k++){
      int c = l + 64*k;
      float p = v[k]*inv + 1e-8f;
      lt[c*16 + (w*4+q)] = (c<CC)? f2bf(p) : (unsigned short)0;
    }
  }
  __syncthreads();
  #pragma unroll
  for(int k=0;k<4;k++){
    int c = t + 256*k;
    us8 a = *(const us8*)&lt[c*16];
    us8 b = *(const us8*)&lt[c*16+8];
    *(us8*)&PbT[(size_t)c*NN + i0] = a;
    *(us8*)&PbT[(size_t)c*NN + i0 + 8] = b;
  }
}

// ---- K5: GEMM1: Tt[c][d] += sum_k PbT[c][k]*FbT[d][k], split-K=16, fp32 atomics
__global__ __launch_bounds__(256,2) void k_gemm1(const unsigned short* __restrict__ A,  // PbT [1024][8192]
                                                 const unsigned short* __restrict__ B,  // FbT [512][8192]
                                                 float* __restrict__ Tt){
  __shared__ unsigned short Al[128*64];
  __shared__ unsigned short Bl[128*64];
  int t = threadIdx.x, l = t&63, w = t>>6;
  int m0 = blockIdx.x*128, n0 = blockIdx.y*128;
  int k0 = blockIdx.z*512;
  int wm = w>>1, wn = w&1;
  f32x4 acc[4][4] = {};
  int srow = w*32 + (l>>3);
  int scl  = (l&7) ^ (srow&7);                 // pre-swizzled source chunk
  const unsigned short* Ab = A + (size_t)(m0 + srow)*NN + k0 + scl*8;
  const unsigned short* Bb = B + (size_t)(n0 + srow)*NN + k0 + scl*8;
  unsigned short* AlB = Al + (w*32)*64;
  unsigned short* BlB = Bl + (w*32)*64;

  for(int kt=0; kt<512; kt+=64){
    __syncthreads();
    #pragma unroll
    for(int q=0;q<4;q++){
      gload_lds16(Ab + (size_t)q*8*NN + kt, AlB + q*8*64);
      gload_lds16(Bb + (size_t)q*8*NN + kt, BlB + q*8*64);
    }
    asm volatile("s_waitcnt vmcnt(0)" ::: "memory");
    __syncthreads();
    #pragma unroll
    for(int ks=0;ks<2;ks++){
      short8 af[4], bf[4];
      #pragma unroll
      for(int mi=0;mi<4;mi++){
        int r = wm*64 + mi*16 + (l&15);
        int ch = ((ks<<2) + (l>>4)) ^ (r&7);
        af[mi] = *(const short8*)&Al[r*64 + ch*8];
      }
      #pragma unroll
      for(int ni=0;ni<4;ni++){
        int r = wn*64 + ni*16 + (l&15);
        int ch = ((ks<<2) + (l>>4)) ^ (r&7);
        bf[ni] = *(const short8*)&Bl[r*64 + ch*8];
      }
      #pragma unroll
      for(int mi=0;mi<4;mi++)
        #pragma unroll
        for(int ni=0;ni<4;ni++)
          acc[mi][ni] = __builtin_amdgcn_mfma_f32_16x16x32_bf16(af[mi], bf[ni], acc[mi][ni], 0,0,0);
    }
  }
  int rbase = (l>>4)*4;
  #pragma unroll
  for(int mi=0;mi<4;mi++){
    int c = m0 + wm*64 + mi*16 + rbase;
    #pragma unroll
    for(int ni=0;ni<4;ni++){
      int d = n0 + wn*64 + ni*16 + (l&15);
      #pragma unroll
      for(int j=0;j<4;j++)
        atomicAdd(&Tt[(size_t)(c+j)*DD + d], acc[mi][ni][j]);
    }
  }
}

// ---- K6: Tt fp32 -> Ttb bf16
__global__ __launch_bounds__(256) void k_castT(const float* __restrict__ Tt,
                                               unsigned short* __restrict__ Ttb){
  int i = (blockIdx.x*256 + threadIdx.x)*4;
  f32x4 v = *(const f32x4*)&Tt[i];
  us4 u; u[0]=f2bf(v[0]); u[1]=f2bf(v[1]); u[2]=f2bf(v[2]); u[3]=f2bf(v[3]);
  *(us4*)&Ttb[i] = u;
}

// ---- K7: GEMM2: M[i][c] = sum_d F[i][d]*Ttb[c][d]; fused KL epilogue
__global__ __launch_bounds__(256,2) void k_gemm2(const float* __restrict__ F,
                                                 const unsigned short* __restrict__ Bt,   // Ttb [1024][512]
                                                 const unsigned short* __restrict__ PbT,  // [1024][8192]
                                                 const float* __restrict__ invr,
                                                 float* __restrict__ partials){
  __shared__ unsigned short Al[128*64];
  __shared__ unsigned short Bl[128*64];
  __shared__ float red[4];
  int t = threadIdx.x, l = t&63, w = t>>6;
  int m0 = blockIdx.x*128, n0 = blockIdx.y*128;
  int wm = w>>1, wn = w&1;
  f32x4 acc[4][4] = {};
  int srow = w*32 + (l>>3);
  int scl  = (l&7) ^ (srow&7);
  const unsigned short* Bb = Bt + (size_t)(n0 + srow)*DD + scl*8;
  unsigned short* BlB = Bl + (w*32)*64;
  int ary = t>>4, acx = t&15;

  for(int kt=0; kt<512; kt+=64){
    __syncthreads();
    #pragma unroll
    for(int q=0;q<4;q++)
      gload_lds16(Bb + (size_t)q*8*DD + kt, BlB + q*8*64);
    // A staged from fp32 F with convert + swizzled ds_write
    #pragma unroll
    for(int rr=0;rr<8;rr++){
      int row = rr*16 + ary;
      f32x4 fv = *(const f32x4*)&F[(size_t)(m0+row)*DD + kt + acx*4];
      us4 u; u[0]=f2bf(fv[0]); u[1]=f2bf(fv[1]); u[2]=f2bf(fv[2]); u[3]=f2bf(fv[3]);
      int chS = (acx>>1) ^ (row&7);
      *(us4*)&Al[row*64 + chS*8 + (acx&1)*4] = u;
    }
    asm volatile("s_waitcnt vmcnt(0)" ::: "memory");
    __syncthreads();
    #pragma unroll
    for(int ks=0;ks<2;ks++){
      short8 af[4], bf[4];
      #pragma unroll
      for(int mi=0;mi<4;mi++){
        int r = wm*64 + mi*16 + (l&15);
        int ch = ((ks<<2) + (l>>4)) ^ (r&7);
        af[mi] = *(const short8*)&Al[r*64 + ch*8];
      }
      #pragma unroll
      for(int ni=0;ni<4;ni++){
        int r = wn*64 + ni*16 + (l&15);
        int ch = ((ks<<2) + (l>>4)) ^ (r&7);
        bf[ni] = *(const short8*)&Bl[r*64 + ch*8];
      }
      #pragma unroll
      for(int mi=0;mi<4;mi++)
        #pragma unroll
        for(int ni=0;ni<4;ni++)
          acc[mi][ni] = __builtin_amdgcn_mfma_f32_16x16x32_bf16(af[mi], bf[ni], acc[mi][ni], 0,0,0);
    }
  }
  // KL epilogue
  float kl = 0.f;
  int rbase = (l>>4)*4;
  #pragma unroll
  for(int mi=0;mi<4;mi++){
    int i_base = m0 + wm*64 + mi*16 + rbase;
    f32x4 ir4 = *(const f32x4*)&invr[i_base];
    #pragma unroll
    for(int ni=0;ni<4;ni++){
      int c = n0 + wn*64 + ni*16 + (l&15);
      if(c < CC){
        us4 p4 = *(const us4*)&PbT[(size_t)c*NN + i_base];
        #pragma unroll
        for(int j=0;j<4;j++){
          float p = bf2f(p4[j]);
          float ws = (acc[mi][ni][j] - p) * ir4[j];
          kl += ws * logf(ws/p);
        }
      }
    }
  }
  kl = waveRedSum(kl);
  if(l==0) red[w]=kl;
  __syncthreads();
  if(t==0) partials[blockIdx.y*64 + blockIdx.x] = red[0]+red[1]+red[2]+red[3];
}

// ---- K8: finalize
__global__ __launch_bounds__(64) void k_finalize(const float* __restrict__ partials,
                                                 float* __restrict__ out){
  int l = threadIdx.x;
  double s = 0.0;
  for(int j=l; j<512; j+=64) s += (double)partials[j];
  #pragma unroll
  for(int o=32;o;o>>=1) s += __shfl_xor(s,o,64);
  if(l==0) out[0] = (float)(s / (double)NN);
}

extern "C" void kernel_launch(void* const* d_in, const int* in_sizes, int n_in,
                              void* d_out, int out_size, void* d_ws, size_t ws_size,
                              hipStream_t stream){
  const float* F = (const float*)d_in[0];   // [8192][512]
  const float* L = (const float*)d_in[1];   // [8192][1000]
  float* out = (float*)d_out;

  unsigned char* w8 = (unsigned char*)d_ws;
  unsigned short* FbT = (unsigned short*)w8;                 // 512*8192*2   = 8 MB
  unsigned short* PbT = (unsigned short*)(w8 + 8388608);     // 1024*8192*2  = 16 MB
  float* Tt           = (float*)(w8 + 8388608 + 16777216);   // 1024*512*4   = 2 MB
  unsigned short* Ttb = (unsigned short*)(w8 + 27262976);    // 1024*512*2   = 1 MB
  float* gpart        = (float*)(w8 + 28311552);             // 128*512*4    = 256 KB
  float* g            = (float*)(w8 + 28573696);             // 512*4
  float* invr         = (float*)(w8 + 28575744);             // 8192*4
  float* partials     = (float*)(w8 + 28608512);             // 512*4

  hipLaunchKernelGGL(k_castF,    dim3(128,8),  dim3(256), 0, stream, F, FbT, gpart, Tt);
  hipLaunchKernelGGL(k_gred,     dim3(1),      dim3(512), 0, stream, gpart, g);
  hipLaunchKernelGGL(k_invr,     dim3(2048),   dim3(256), 0, stream, F, g, invr);
  hipLaunchKernelGGL(k_softmaxT, dim3(512),    dim3(256), 0, stream, L, PbT);
  hipLaunchKernelGGL(k_gemm1,    dim3(8,4,16), dim3(256), 0, stream, PbT, FbT, Tt);
  hipLaunchKernelGGL(k_castT,    dim3(512),    dim3(256), 0, stream, Tt, Ttb);
  hipLaunchKernelGGL(k_gemm2,    dim3(64,8),   dim3(256), 0, stream, F, Ttb, PbT, invr, partials);
  hipLaunchKernelGGL(k_finalize, dim3(1),      dim3(64),  0, stream, partials, out);
}

// Round 4
// 98.062 us; speedup vs baseline: 6.3915x; 1.1510x over previous
//
#include <hip/hip_runtime.h>
#include <math.h>

#define NN 8192
#define DD 512
#define CC 1000
#define CP 1024   // padded C

typedef __attribute__((ext_vector_type(8))) short short8;     // bf16x8 MFMA frag
typedef __attribute__((ext_vector_type(4))) float f32x4;
typedef __attribute__((ext_vector_type(2))) float f32x2;
typedef __attribute__((ext_vector_type(4))) unsigned short us4;
typedef __attribute__((ext_vector_type(8))) unsigned short us8;

__device__ __forceinline__ float bf2f(unsigned short u){
  union{unsigned int i; float f;} v; v.i = ((unsigned int)u)<<16; return v.f;
}
__device__ __forceinline__ unsigned short f2bf(float f){
  union{float f; unsigned int i;} v; v.f = f;
  unsigned int r = v.i + 0x7FFF + ((v.i>>16)&1);   // RNE
  return (unsigned short)(r>>16);
}
__device__ __forceinline__ float waveRedSum(float v){
  #pragma unroll
  for(int o=32;o;o>>=1) v += __shfl_xor(v,o,64);
  return v;
}
__device__ __forceinline__ float waveRedMax(float v){
  #pragma unroll
  for(int o=32;o;o>>=1) v = fmaxf(v,__shfl_xor(v,o,64));
  return v;
}
__device__ __forceinline__ void gload_lds16(const void* g, void* l){
  __builtin_amdgcn_global_load_lds((const __attribute__((address_space(1))) void*)g,
                                   (__attribute__((address_space(3))) void*)l, 16, 0, 0);
}

// ---- K1: F (fp32) -> FbT (bf16, [512][8192]) + fp32 colsum partials gpart[128][512]
__global__ __launch_bounds__(256) void k_castF(const float* __restrict__ F,
                                               unsigned short* __restrict__ FbT,
                                               float* __restrict__ gpart){
  __shared__ unsigned short lds[64*68];
  __shared__ float gq[16*64];
  int t = threadIdx.x;
  int i0 = blockIdx.x*64, d0 = blockIdx.y*64;
  int cx = t&15, ry = t>>4;
  float ca0=0.f,ca1=0.f,ca2=0.f,ca3=0.f;
  #pragma unroll
  for(int rr=0;rr<4;rr++){
    int row = rr*16 + ry;
    f32x4 fv = *(const f32x4*)&F[(size_t)(i0+row)*DD + d0 + cx*4];
    us4 u; u[0]=f2bf(fv[0]); u[1]=f2bf(fv[1]); u[2]=f2bf(fv[2]); u[3]=f2bf(fv[3]);
    *(us4*)&lds[row*68 + cx*4] = u;
    ca0+=fv[0]; ca1+=fv[1]; ca2+=fv[2]; ca3+=fv[3];
  }
  {
    f32x4 cv; cv[0]=ca0; cv[1]=ca1; cv[2]=ca2; cv[3]=ca3;
    *(f32x4*)&gq[ry*64 + cx*4] = cv;
  }
  __syncthreads();
  // transposed write: FbT[d][i]
  #pragma unroll
  for(int rr=0;rr<4;rr++){
    int d = rr*16 + ry;
    us4 u;
    #pragma unroll
    for(int q=0;q<4;q++) u[q] = lds[(cx*4+q)*68 + d];
    *(us4*)&FbT[(size_t)(d0+d)*NN + i0 + cx*4] = u;
  }
  __syncthreads();
  if(t<64){
    float s=0.f;
    #pragma unroll
    for(int j=0;j<16;j++) s += gq[j*64+t];
    gpart[blockIdx.x*DD + d0 + t] = s;
  }
}

// ---- K2: g[d] = sum over 128 partial groups (deterministic)
__global__ __launch_bounds__(512) void k_gred(const float* __restrict__ gpart,
                                              float* __restrict__ g){
  int t = threadIdx.x;
  float s=0.f;
  for(int j=0;j<128;j++) s += gpart[j*DD + t];
  g[t] = s;
}

// ---- K3: invr[i] = 1/(f_i . g - 1)   (fp32, one wave per row)
__global__ __launch_bounds__(256) void k_invr(const float* __restrict__ F,
                                              const float* __restrict__ g,
                                              float* __restrict__ invr){
  int t = threadIdx.x, l = t&63, w = t>>6;
  int row = blockIdx.x*4 + w;
  const float* fr = F + (size_t)row*DD + l*8;
  f32x4 a = *(const f32x4*)fr, b = *(const f32x4*)(fr+4);
  f32x4 ga = *(const f32x4*)&g[l*8], gb = *(const f32x4*)&g[l*8+4];
  float s = a[0]*ga[0]+a[1]*ga[1]+a[2]*ga[2]+a[3]*ga[3]
          + b[0]*gb[0]+b[1]*gb[1]+b[2]*gb[2]+b[3]*gb[3];
  s = waveRedSum(s);
  if(l==0) invr[row] = 1.0f/(s - 1.0f);
}

// ---- K4: softmax + transpose: logits [8192][1000] -> PbT bf16 [1024][8192]
__global__ __launch_bounds__(256) void k_softmaxT(const float* __restrict__ L,
                                                  unsigned short* __restrict__ PbT){
  __shared__ unsigned short lt[CP*16];   // [c][rr] 32KB
  int t = threadIdx.x, l = t&63, w = t>>6;
  int i0 = blockIdx.x*16;
  #pragma unroll
  for(int q=0;q<4;q++){
    int row = i0 + w*4 + q;
    const float* lr = L + (size_t)row*CC;
    float v[16]; float mx = -1e30f;
    #pragma unroll
    for(int k=0;k<16;k++){ int c = l + 64*k; v[k] = (c<CC)? lr[c] : -1e30f; mx = fmaxf(mx,v[k]); }
    mx = waveRedMax(mx);
    float s = 0.f;
    #pragma unroll
    for(int k=0;k<16;k++){ v[k] = expf(v[k]-mx); s += v[k]; }
    s = waveRedSum(s);
    float inv = 1.0f/s;
    #pragma unroll
    for(int k=0;k<16;k++){
      int c = l + 64*k;
      float p = v[k]*inv + 1e-8f;
      lt[c*16 + (w*4+q)] = (c<CC)? f2bf(p) : (unsigned short)0;
    }
  }
  __syncthreads();
  #pragma unroll
  for(int k=0;k<4;k++){
    int c = t + 256*k;
    us8 a = *(const us8*)&lt[c*16];
    us8 b = *(const us8*)&lt[c*16+8];
    *(us8*)&PbT[(size_t)c*NN + i0] = a;
    *(us8*)&PbT[(size_t)c*NN + i0 + 8] = b;
  }
}

// ---- K5: GEMM1: Tp[z][c][d] = sum_{k in chunk z} PbT[c][k]*FbT[d][k]
//      split-K=16 into PRIVATE partial buffers (no atomics), plain stores.
__global__ __launch_bounds__(256,2) void k_gemm1(const unsigned short* __restrict__ A,  // PbT [1024][8192]
                                                 const unsigned short* __restrict__ B,  // FbT [512][8192]
                                                 float* __restrict__ Tp){
  __shared__ unsigned short Al[128*64];
  __shared__ unsigned short Bl[128*64];
  int t = threadIdx.x, l = t&63, w = t>>6;
  int m0 = blockIdx.x*128, n0 = blockIdx.y*128;
  int k0 = blockIdx.z*512;
  int wm = w>>1, wn = w&1;
  f32x4 acc[4][4] = {};
  int srow = w*32 + (l>>3);
  int scl  = (l&7) ^ (srow&7);                 // pre-swizzled source chunk
  const unsigned short* Ab = A + (size_t)(m0 + srow)*NN + k0 + scl*8;
  const unsigned short* Bb = B + (size_t)(n0 + srow)*NN + k0 + scl*8;
  unsigned short* AlB = Al + (w*32)*64;
  unsigned short* BlB = Bl + (w*32)*64;

  for(int kt=0; kt<512; kt+=64){
    __syncthreads();
    #pragma unroll
    for(int q=0;q<4;q++){
      gload_lds16(Ab + (size_t)q*8*NN + kt, AlB + q*8*64);
      gload_lds16(Bb + (size_t)q*8*NN + kt, BlB + q*8*64);
    }
    asm volatile("s_waitcnt vmcnt(0)" ::: "memory");
    __syncthreads();
    #pragma unroll
    for(int ks=0;ks<2;ks++){
      short8 af[4], bf[4];
      #pragma unroll
      for(int mi=0;mi<4;mi++){
        int r = wm*64 + mi*16 + (l&15);
        int ch = ((ks<<2) + (l>>4)) ^ (r&7);
        af[mi] = *(const short8*)&Al[r*64 + ch*8];
      }
      #pragma unroll
      for(int ni=0;ni<4;ni++){
        int r = wn*64 + ni*16 + (l&15);
        int ch = ((ks<<2) + (l>>4)) ^ (r&7);
        bf[ni] = *(const short8*)&Bl[r*64 + ch*8];
      }
      #pragma unroll
      for(int mi=0;mi<4;mi++)
        #pragma unroll
        for(int ni=0;ni<4;ni++)
          acc[mi][ni] = __builtin_amdgcn_mfma_f32_16x16x32_bf16(af[mi], bf[ni], acc[mi][ni], 0,0,0);
    }
  }
  float* Tz = Tp + (size_t)blockIdx.z*CP*DD;
  int rbase = (l>>4)*4;
  #pragma unroll
  for(int mi=0;mi<4;mi++){
    int c = m0 + wm*64 + mi*16 + rbase;
    #pragma unroll
    for(int ni=0;ni<4;ni++){
      int d = n0 + wn*64 + ni*16 + (l&15);
      #pragma unroll
      for(int j=0;j<4;j++)
        Tz[(size_t)(c+j)*DD + d] = acc[mi][ni][j];
    }
  }
}

// ---- K6: reduce 16 partials + cast to bf16: Ttb = bf16(sum_z Tp[z])
__global__ __launch_bounds__(256) void k_redT(const float* __restrict__ Tp,
                                              unsigned short* __restrict__ Ttb){
  size_t i = ((size_t)blockIdx.x*256 + (size_t)threadIdx.x)*8;
  f32x4 s0 = {0.f,0.f,0.f,0.f}, s1 = {0.f,0.f,0.f,0.f};
  #pragma unroll
  for(int z=0;z<16;z++){
    const f32x4* b = (const f32x4*)(Tp + (size_t)z*CP*DD + i);
    s0 += b[0]; s1 += b[1];
  }
  us8 u;
  u[0]=f2bf(s0[0]); u[1]=f2bf(s0[1]); u[2]=f2bf(s0[2]); u[3]=f2bf(s0[3]);
  u[4]=f2bf(s1[0]); u[5]=f2bf(s1[1]); u[6]=f2bf(s1[2]); u[7]=f2bf(s1[3]);
  *(us8*)&Ttb[i] = u;
}

// ---- K7: GEMM2: M[i][c] = sum_d F[i][d]*Ttb[c][d]; fused KL epilogue
__global__ __launch_bounds__(256,2) void k_gemm2(const float* __restrict__ F,
                                                 const unsigned short* __restrict__ Bt,   // Ttb [1024][512]
                                                 const unsigned short* __restrict__ PbT,  // [1024][8192]
                                                 const float* __restrict__ invr,
                                                 float* __restrict__ partials){
  __shared__ unsigned short Al[128*64];
  __shared__ unsigned short Bl[128*64];
  __shared__ float red[4];
  int t = threadIdx.x, l = t&63, w = t>>6;
  int m0 = blockIdx.x*128, n0 = blockIdx.y*128;
  int wm = w>>1, wn = w&1;
  f32x4 acc[4][4] = {};
  int srow = w*32 + (l>>3);
  int scl  = (l&7) ^ (srow&7);
  const unsigned short* Bb = Bt + (size_t)(n0 + srow)*DD + scl*8;
  unsigned short* BlB = Bl + (w*32)*64;
  int ary = t>>4, acx = t&15;

  for(int kt=0; kt<512; kt+=64){
    __syncthreads();
    #pragma unroll
    for(int q=0;q<4;q++)
      gload_lds16(Bb + (size_t)q*8*DD + kt, BlB + q*8*64);
    // A staged from fp32 F with convert + swizzled ds_write
    #pragma unroll
    for(int rr=0;rr<8;rr++){
      int row = rr*16 + ary;
      f32x4 fv = *(const f32x4*)&F[(size_t)(m0+row)*DD + kt + acx*4];
      us4 u; u[0]=f2bf(fv[0]); u[1]=f2bf(fv[1]); u[2]=f2bf(fv[2]); u[3]=f2bf(fv[3]);
      int chS = (acx>>1) ^ (row&7);
      *(us4*)&Al[row*64 + chS*8 + (acx&1)*4] = u;
    }
    asm volatile("s_waitcnt vmcnt(0)" ::: "memory");
    __syncthreads();
    #pragma unroll
    for(int ks=0;ks<2;ks++){
      short8 af[4], bf[4];
      #pragma unroll
      for(int mi=0;mi<4;mi++){
        int r = wm*64 + mi*16 + (l&15);
        int ch = ((ks<<2) + (l>>4)) ^ (r&7);
        af[mi] = *(const short8*)&Al[r*64 + ch*8];
      }
      #pragma unroll
      for(int ni=0;ni<4;ni++){
        int r = wn*64 + ni*16 + (l&15);
        int ch = ((ks<<2) + (l>>4)) ^ (r&7);
        bf[ni] = *(const short8*)&Bl[r*64 + ch*8];
      }
      #pragma unroll
      for(int mi=0;mi<4;mi++)
        #pragma unroll
        for(int ni=0;ni<4;ni++)
          acc[mi][ni] = __builtin_amdgcn_mfma_f32_16x16x32_bf16(af[mi], bf[ni], acc[mi][ni], 0,0,0);
    }
  }
  // KL epilogue
  float kl = 0.f;
  int rbase = (l>>4)*4;
  #pragma unroll
  for(int mi=0;mi<4;mi++){
    int i_base = m0 + wm*64 + mi*16 + rbase;
    f32x4 ir4 = *(const f32x4*)&invr[i_base];
    #pragma unroll
    for(int ni=0;ni<4;ni++){
      int c = n0 + wn*64 + ni*16 + (l&15);
      if(c < CC){
        us4 p4 = *(const us4*)&PbT[(size_t)c*NN + i_base];
        #pragma unroll
        for(int j=0;j<4;j++){
          float p = bf2f(p4[j]);
          float ws = (acc[mi][ni][j] - p) * ir4[j];
          kl += ws * logf(ws/p);
        }
      }
    }
  }
  kl = waveRedSum(kl);
  if(l==0) red[w]=kl;
  __syncthreads();
  if(t==0) partials[blockIdx.y*64 + blockIdx.x] = red[0]+red[1]+red[2]+red[3];
}

// ---- K8: finalize
__global__ __launch_bounds__(64) void k_finalize(const float* __restrict__ partials,
                                                 float* __restrict__ out){
  int l = threadIdx.x;
  double s = 0.0;
  for(int j=l; j<512; j+=64) s += (double)partials[j];
  #pragma unroll
  for(int o=32;o;o>>=1) s += __shfl_xor(s,o,64);
  if(l==0) out[0] = (float)(s / (double)NN);
}

extern "C" void kernel_launch(void* const* d_in, const int* in_sizes, int n_in,
                              void* d_out, int out_size, void* d_ws, size_t ws_size,
                              hipStream_t stream){
  const float* F = (const float*)d_in[0];   // [8192][512]
  const float* L = (const float*)d_in[1];   // [8192][1000]
  float* out = (float*)d_out;

  unsigned char* w8 = (unsigned char*)d_ws;
  unsigned short* FbT = (unsigned short*)w8;                   // 512*8192*2      = 8 MB
  unsigned short* PbT = (unsigned short*)(w8 + (8u<<20));      // 1024*8192*2     = 16 MB
  float* Tp           = (float*)(w8 + (24u<<20));              // 16*1024*512*4   = 32 MB
  unsigned short* Ttb = (unsigned short*)(w8 + (56u<<20));     // 1024*512*2      = 1 MB
  float* gpart        = (float*)(w8 + (57u<<20));              // 128*512*4       = 256 KB
  float* g            = (float*)(w8 + (57u<<20) + 262144);     // 512*4
  float* invr         = (float*)(w8 + (57u<<20) + 264192);     // 8192*4
  float* partials     = (float*)(w8 + (57u<<20) + 296960);     // 512*4

  hipLaunchKernelGGL(k_castF,    dim3(128,8),  dim3(256), 0, stream, F, FbT, gpart);
  hipLaunchKernelGGL(k_gred,     dim3(1),      dim3(512), 0, stream, gpart, g);
  hipLaunchKernelGGL(k_invr,     dim3(2048),   dim3(256), 0, stream, F, g, invr);
  hipLaunchKernelGGL(k_softmaxT, dim3(512),    dim3(256), 0, stream, L, PbT);
  hipLaunchKernelGGL(k_gemm1,    dim3(8,4,16), dim3(256), 0, stream, PbT, FbT, Tp);
  hipLaunchKernelGGL(k_redT,     dim3(256),    dim3(256), 0, stream, Tp, Ttb);
  hipLaunchKernelGGL(k_gemm2,    dim3(64,8),   dim3(256), 0, stream, F, Ttb, PbT, invr, partials);
  hipLaunchKernelGGL(k_finalize, dim3(1),      dim3(64),  0, stream, partials, out);
}

// Round 5
// 83.589 us; speedup vs baseline: 7.4981x; 1.1731x over previous
//
#include <hip/hip_runtime.h>
#include <math.h>

#define NN 8192
#define DD 512
#define CC 1000
#define CP 1024   // padded C

typedef __attribute__((ext_vector_type(8))) short short8;     // bf16x8 MFMA frag
typedef __attribute__((ext_vector_type(4))) float f32x4;
typedef __attribute__((ext_vector_type(4))) unsigned short us4;
typedef __attribute__((ext_vector_type(8))) unsigned short us8;
typedef __attribute__((ext_vector_type(4))) unsigned int ui4;

__device__ __forceinline__ float bf2f(unsigned short u){
  union{unsigned int i; float f;} v; v.i = ((unsigned int)u)<<16; return v.f;
}
__device__ __forceinline__ unsigned short f2bf(float f){
  union{float f; unsigned int i;} v; v.f = f;
  unsigned int r = v.i + 0x7FFF + ((v.i>>16)&1);   // RNE
  return (unsigned short)(r>>16);
}
__device__ __forceinline__ float waveRedSum(float v){
  #pragma unroll
  for(int o=32;o;o>>=1) v += __shfl_xor(v,o,64);
  return v;
}
__device__ __forceinline__ float waveRedMax(float v){
  #pragma unroll
  for(int o=32;o;o>>=1) v = fmaxf(v,__shfl_xor(v,o,64));
  return v;
}
__device__ __forceinline__ void gload_lds16(const void* g, void* l){
  __builtin_amdgcn_global_load_lds((const __attribute__((address_space(1))) void*)g,
                                   (__attribute__((address_space(3))) void*)l, 16, 0, 0);
}

// ---- K1: F (fp32) -> FbT bf16 [512][8192] + Fb bf16 [8192][512] + colsum partials
__global__ __launch_bounds__(256) void k_castF(const float* __restrict__ F,
                                               unsigned short* __restrict__ FbT,
                                               unsigned short* __restrict__ Fb,
                                               float* __restrict__ gpart){
  __shared__ unsigned short lds[64*68];
  __shared__ float gq[16*64];
  int t = threadIdx.x;
  int i0 = blockIdx.x*64, d0 = blockIdx.y*64;
  int cx = t&15, ry = t>>4;
  float ca0=0.f,ca1=0.f,ca2=0.f,ca3=0.f;
  #pragma unroll
  for(int rr=0;rr<4;rr++){
    int row = rr*16 + ry;
    f32x4 fv = *(const f32x4*)&F[(size_t)(i0+row)*DD + d0 + cx*4];
    us4 u; u[0]=f2bf(fv[0]); u[1]=f2bf(fv[1]); u[2]=f2bf(fv[2]); u[3]=f2bf(fv[3]);
    *(us4*)&lds[row*68 + cx*4] = u;
    *(us4*)&Fb[(size_t)(i0+row)*DD + d0 + cx*4] = u;
    ca0+=fv[0]; ca1+=fv[1]; ca2+=fv[2]; ca3+=fv[3];
  }
  {
    f32x4 cv; cv[0]=ca0; cv[1]=ca1; cv[2]=ca2; cv[3]=ca3;
    *(f32x4*)&gq[ry*64 + cx*4] = cv;
  }
  __syncthreads();
  // transposed write: FbT[d][i]
  #pragma unroll
  for(int rr=0;rr<4;rr++){
    int d = rr*16 + ry;
    us4 u;
    #pragma unroll
    for(int q=0;q<4;q++) u[q] = lds[(cx*4+q)*68 + d];
    *(us4*)&FbT[(size_t)(d0+d)*NN + i0 + cx*4] = u;
  }
  __syncthreads();
  if(t<64){
    float s=0.f;
    #pragma unroll
    for(int j=0;j<16;j++) s += gq[j*64+t];
    gpart[blockIdx.x*DD + d0 + t] = s;
  }
}

// ---- K2: g[d] = sum over 128 partial groups (deterministic)
__global__ __launch_bounds__(512) void k_gred(const float* __restrict__ gpart,
                                              float* __restrict__ g){
  int t = threadIdx.x;
  float s=0.f;
  for(int j=0;j<128;j++) s += gpart[j*DD + t];
  g[t] = s;
}

// ---- K4: softmax + transpose: logits [8192][1000] -> PbT bf16 [1024][8192]
//      LDS layout [row-pair][c] (uint), conflict-free writes AND reads.
__global__ __launch_bounds__(256) void k_softmaxT(const float* __restrict__ L,
                                                  unsigned short* __restrict__ PbT){
  __shared__ unsigned int lt[8][1028];   // pad 4 words per row
  int t = threadIdx.x, l = t&63, w = t>>6;
  int i0 = blockIdx.x*16;
  #pragma unroll
  for(int q=0;q<4;q++){
    int rr = w*4 + q;
    int row = i0 + rr;
    const float* lr = L + (size_t)row*CC;
    float v[16]; float mx = -1e30f;
    #pragma unroll
    for(int k=0;k<16;k++){ int c = l + 64*k; v[k] = (c<CC)? lr[c] : -1e30f; mx = fmaxf(mx,v[k]); }
    mx = waveRedMax(mx);
    float s = 0.f;
    #pragma unroll
    for(int k=0;k<16;k++){ v[k] = expf(v[k]-mx); s += v[k]; }
    s = waveRedSum(s);
    float inv = 1.0f/s;
    #pragma unroll
    for(int k=0;k<16;k++){
      int c = l + 64*k;
      float p = v[k]*inv + 1e-8f;
      unsigned short h = (c<CC)? f2bf(p) : (unsigned short)0;
      *((unsigned short*)&lt[rr>>1][c] + (rr&1)) = h;
    }
  }
  __syncthreads();
  #pragma unroll
  for(int k=0;k<4;k++){
    int c = t + 256*k;
    ui4 a, b;
    #pragma unroll
    for(int j=0;j<4;j++){ a[j] = lt[j][c]; b[j] = lt[j+4][c]; }
    *(ui4*)&PbT[(size_t)c*NN + i0]     = a;
    *(ui4*)&PbT[(size_t)c*NN + i0 + 8] = b;
  }
}

// ---- K5: GEMM1: Tp[z][c][d] = sum_{k in chunk z} PbT[c][k]*FbT[d][k]
//      split-K=16 into PRIVATE partial buffers (no atomics), plain stores.
__global__ __launch_bounds__(256,2) void k_gemm1(const unsigned short* __restrict__ A,  // PbT [1024][8192]
                                                 const unsigned short* __restrict__ B,  // FbT [512][8192]
                                                 float* __restrict__ Tp){
  __shared__ unsigned short Al[128*64];
  __shared__ unsigned short Bl[128*64];
  int t = threadIdx.x, l = t&63, w = t>>6;
  int m0 = blockIdx.x*128, n0 = blockIdx.y*128;
  int k0 = blockIdx.z*512;
  int wm = w>>1, wn = w&1;
  f32x4 acc[4][4] = {};
  int srow = w*32 + (l>>3);
  int scl  = (l&7) ^ (srow&7);                 // pre-swizzled source chunk
  const unsigned short* Ab = A + (size_t)(m0 + srow)*NN + k0 + scl*8;
  const unsigned short* Bb = B + (size_t)(n0 + srow)*NN + k0 + scl*8;
  unsigned short* AlB = Al + (w*32)*64;
  unsigned short* BlB = Bl + (w*32)*64;

  for(int kt=0; kt<512; kt+=64){
    __syncthreads();
    #pragma unroll
    for(int q=0;q<4;q++){
      gload_lds16(Ab + (size_t)q*8*NN + kt, AlB + q*8*64);
      gload_lds16(Bb + (size_t)q*8*NN + kt, BlB + q*8*64);
    }
    asm volatile("s_waitcnt vmcnt(0)" ::: "memory");
    __syncthreads();
    #pragma unroll
    for(int ks=0;ks<2;ks++){
      short8 af[4], bf[4];
      #pragma unroll
      for(int mi=0;mi<4;mi++){
        int r = wm*64 + mi*16 + (l&15);
        int ch = ((ks<<2) + (l>>4)) ^ (r&7);
        af[mi] = *(const short8*)&Al[r*64 + ch*8];
      }
      #pragma unroll
      for(int ni=0;ni<4;ni++){
        int r = wn*64 + ni*16 + (l&15);
        int ch = ((ks<<2) + (l>>4)) ^ (r&7);
        bf[ni] = *(const short8*)&Bl[r*64 + ch*8];
      }
      #pragma unroll
      for(int mi=0;mi<4;mi++)
        #pragma unroll
        for(int ni=0;ni<4;ni++)
          acc[mi][ni] = __builtin_amdgcn_mfma_f32_16x16x32_bf16(af[mi], bf[ni], acc[mi][ni], 0,0,0);
    }
  }
  float* Tz = Tp + (size_t)blockIdx.z*CP*DD;
  int rbase = (l>>4)*4;
  #pragma unroll
  for(int mi=0;mi<4;mi++){
    int c = m0 + wm*64 + mi*16 + rbase;
    #pragma unroll
    for(int ni=0;ni<4;ni++){
      int d = n0 + wn*64 + ni*16 + (l&15);
      #pragma unroll
      for(int j=0;j<4;j++)
        Tz[(size_t)(c+j)*DD + d] = acc[mi][ni][j];
    }
  }
}

// ---- K6: reduce 16 partials + cast to bf16 (phase 1) AND invr (phase 2)
__global__ __launch_bounds__(256) void k_redT(const float* __restrict__ Tp,
                                              const unsigned short* __restrict__ Fb,
                                              const float* __restrict__ g,
                                              unsigned short* __restrict__ Ttb,
                                              float* __restrict__ invr){
  int t = threadIdx.x;
  // phase 1: Ttb = bf16(sum_z Tp[z]) ; 256 blocks x 256 threads x 8 elems = CP*DD
  size_t i = ((size_t)blockIdx.x*256 + (size_t)t)*8;
  f32x4 s0 = {0.f,0.f,0.f,0.f}, s1 = {0.f,0.f,0.f,0.f};
  #pragma unroll
  for(int z=0;z<16;z++){
    const f32x4* b = (const f32x4*)(Tp + (size_t)z*CP*DD + i);
    s0 += b[0]; s1 += b[1];
  }
  us8 u;
  u[0]=f2bf(s0[0]); u[1]=f2bf(s0[1]); u[2]=f2bf(s0[2]); u[3]=f2bf(s0[3]);
  u[4]=f2bf(s1[0]); u[5]=f2bf(s1[1]); u[6]=f2bf(s1[2]); u[7]=f2bf(s1[3]);
  *(us8*)&Ttb[i] = u;
  // phase 2: invr for rows blockIdx.x*32 .. +31 (8 lanes per row)
  int row = blockIdx.x*32 + (t>>3);
  int seg = (t&7)*64;
  const unsigned short* fr = Fb + (size_t)row*DD + seg;
  const float* gr = g + seg;
  float s = 0.f;
  #pragma unroll
  for(int j=0;j<8;j++){
    us8 f8 = *(const us8*)&fr[j*8];
    f32x4 ga = *(const f32x4*)&gr[j*8];
    f32x4 gb = *(const f32x4*)&gr[j*8+4];
    s += bf2f(f8[0])*ga[0]+bf2f(f8[1])*ga[1]+bf2f(f8[2])*ga[2]+bf2f(f8[3])*ga[3]
       + bf2f(f8[4])*gb[0]+bf2f(f8[5])*gb[1]+bf2f(f8[6])*gb[2]+bf2f(f8[7])*gb[3];
  }
  s += __shfl_xor(s,1,64); s += __shfl_xor(s,2,64); s += __shfl_xor(s,4,64);
  if((t&7)==0) invr[row] = 1.0f/(s - 1.0f);
}

// ---- K7: GEMM2: M[i][c] = sum_d Fb[i][d]*Ttb[c][d]; fused KL epilogue
__global__ __launch_bounds__(256,2) void k_gemm2(const unsigned short* __restrict__ Fb,   // [8192][512]
                                                 const unsigned short* __restrict__ Bt,   // Ttb [1024][512]
                                                 const unsigned short* __restrict__ PbT,  // [1024][8192]
                                                 const float* __restrict__ invr,
                                                 float* __restrict__ partials){
  __shared__ unsigned short Al[128*64];
  __shared__ unsigned short Bl[128*64];
  __shared__ float red[4];
  int t = threadIdx.x, l = t&63, w = t>>6;
  int m0 = blockIdx.x*128, n0 = blockIdx.y*128;
  int wm = w>>1, wn = w&1;
  f32x4 acc[4][4] = {};
  int srow = w*32 + (l>>3);
  int scl  = (l&7) ^ (srow&7);
  const unsigned short* Ab = Fb + (size_t)(m0 + srow)*DD + scl*8;
  const unsigned short* Bb = Bt + (size_t)(n0 + srow)*DD + scl*8;
  unsigned short* AlB = Al + (w*32)*64;
  unsigned short* BlB = Bl + (w*32)*64;

  for(int kt=0; kt<512; kt+=64){
    __syncthreads();
    #pragma unroll
    for(int q=0;q<4;q++){
      gload_lds16(Ab + (size_t)q*8*DD + kt, AlB + q*8*64);
      gload_lds16(Bb + (size_t)q*8*DD + kt, BlB + q*8*64);
    }
    asm volatile("s_waitcnt vmcnt(0)" ::: "memory");
    __syncthreads();
    #pragma unroll
    for(int ks=0;ks<2;ks++){
      short8 af[4], bf[4];
      #pragma unroll
      for(int mi=0;mi<4;mi++){
        int r = wm*64 + mi*16 + (l&15);
        int ch = ((ks<<2) + (l>>4)) ^ (r&7);
        af[mi] = *(const short8*)&Al[r*64 + ch*8];
      }
      #pragma unroll
      for(int ni=0;ni<4;ni++){
        int r = wn*64 + ni*16 + (l&15);
        int ch = ((ks<<2) + (l>>4)) ^ (r&7);
        bf[ni] = *(const short8*)&Bl[r*64 + ch*8];
      }
      #pragma unroll
      for(int mi=0;mi<4;mi++)
        #pragma unroll
        for(int ni=0;ni<4;ni++)
          acc[mi][ni] = __builtin_amdgcn_mfma_f32_16x16x32_bf16(af[mi], bf[ni], acc[mi][ni], 0,0,0);
    }
  }
  // KL epilogue
  float kl = 0.f;
  int rbase = (l>>4)*4;
  #pragma unroll
  for(int mi=0;mi<4;mi++){
    int i_base = m0 + wm*64 + mi*16 + rbase;
    f32x4 ir4 = *(const f32x4*)&invr[i_base];
    #pragma unroll
    for(int ni=0;ni<4;ni++){
      int c = n0 + wn*64 + ni*16 + (l&15);
      if(c < CC){
        us4 p4 = *(const us4*)&PbT[(size_t)c*NN + i_base];
        #pragma unroll
        for(int j=0;j<4;j++){
          float p = bf2f(p4[j]);
          float ws = (acc[mi][ni][j] - p) * ir4[j];
          kl += ws * logf(ws/p);
        }
      }
    }
  }
  kl = waveRedSum(kl);
  if(l==0) red[w]=kl;
  __syncthreads();
  if(t==0) partials[blockIdx.y*64 + blockIdx.x] = red[0]+red[1]+red[2]+red[3];
}

// ---- K8: finalize
__global__ __launch_bounds__(64) void k_finalize(const float* __restrict__ partials,
                                                 float* __restrict__ out){
  int l = threadIdx.x;
  double s = 0.0;
  for(int j=l; j<512; j+=64) s += (double)partials[j];
  #pragma unroll
  for(int o=32;o;o>>=1) s += __shfl_xor(s,o,64);
  if(l==0) out[0] = (float)(s / (double)NN);
}

extern "C" void kernel_launch(void* const* d_in, const int* in_sizes, int n_in,
                              void* d_out, int out_size, void* d_ws, size_t ws_size,
                              hipStream_t stream){
  const float* F = (const float*)d_in[0];   // [8192][512]
  const float* L = (const float*)d_in[1];   // [8192][1000]
  float* out = (float*)d_out;

  unsigned char* w8 = (unsigned char*)d_ws;
  unsigned short* FbT = (unsigned short*)w8;                   // 512*8192*2      = 8 MB
  unsigned short* PbT = (unsigned short*)(w8 + (8u<<20));      // 1024*8192*2     = 16 MB
  float* Tp           = (float*)(w8 + (24u<<20));              // 16*1024*512*4   = 32 MB
  unsigned short* Ttb = (unsigned short*)(w8 + (56u<<20));     // 1024*512*2      = 1 MB
  unsigned short* Fb  = (unsigned short*)(w8 + (57u<<20));     // 8192*512*2      = 8 MB
  float* gpart        = (float*)(w8 + (65u<<20));              // 128*512*4       = 256 KB
  float* g            = (float*)(w8 + (65u<<20) + 262144);     // 512*4
  float* invr         = (float*)(w8 + (65u<<20) + 264192);     // 8192*4
  float* partials     = (float*)(w8 + (65u<<20) + 296960);     // 512*4

  hipLaunchKernelGGL(k_castF,    dim3(128,8),  dim3(256), 0, stream, F, FbT, Fb, gpart);
  hipLaunchKernelGGL(k_gred,     dim3(1),      dim3(512), 0, stream, gpart, g);
  hipLaunchKernelGGL(k_softmaxT, dim3(512),    dim3(256), 0, stream, L, PbT);
  hipLaunchKernelGGL(k_gemm1,    dim3(8,4,16), dim3(256), 0, stream, PbT, FbT, Tp);
  hipLaunchKernelGGL(k_redT,     dim3(256),    dim3(256), 0, stream, Tp, Fb, g, Ttb, invr);
  hipLaunchKernelGGL(k_gemm2,    dim3(64,8),   dim3(256), 0, stream, Fb, Ttb, PbT, invr, partials);
  hipLaunchKernelGGL(k_finalize, dim3(1),      dim3(64),  0, stream, partials, out);
}

// Round 6
// 77.612 us; speedup vs baseline: 8.0755x; 1.0770x over previous
//
#include <hip/hip_runtime.h>
#include <math.h>

#define NN 8192
#define DD 512
#define CC 1000
#define CP 1024   // padded C

typedef __attribute__((ext_vector_type(8))) short short8;     // bf16x8 MFMA frag
typedef __attribute__((ext_vector_type(4))) float f32x4;
typedef __attribute__((ext_vector_type(4))) unsigned short us4;
typedef __attribute__((ext_vector_type(8))) unsigned short us8;
typedef __attribute__((ext_vector_type(4))) unsigned int ui4;

__device__ __forceinline__ float bf2f(unsigned short u){
  union{unsigned int i; float f;} v; v.i = ((unsigned int)u)<<16; return v.f;
}
__device__ __forceinline__ unsigned short f2bf(float f){
  union{float f; unsigned int i;} v; v.f = f;
  unsigned int r = v.i + 0x7FFF + ((v.i>>16)&1);   // RNE
  return (unsigned short)(r>>16);
}
__device__ __forceinline__ float waveRedSum(float v){
  #pragma unroll
  for(int o=32;o;o>>=1) v += __shfl_xor(v,o,64);
  return v;
}
__device__ __forceinline__ float waveRedMax(float v){
  #pragma unroll
  for(int o=32;o;o>>=1) v = fmaxf(v,__shfl_xor(v,o,64));
  return v;
}
__device__ __forceinline__ void gload_lds16(const void* g, void* l){
  __builtin_amdgcn_global_load_lds((const __attribute__((address_space(1))) void*)g,
                                   (__attribute__((address_space(3))) void*)l, 16, 0, 0);
}

// ---- K1: F (fp32) -> FbT bf16 [512][8192] + Fb bf16 [8192][512] + colsum partials
__global__ __launch_bounds__(256) void k_castF(const float* __restrict__ F,
                                               unsigned short* __restrict__ FbT,
                                               unsigned short* __restrict__ Fb,
                                               float* __restrict__ gpart){
  __shared__ unsigned short lds[64*68];
  __shared__ float gq[16*64];
  int t = threadIdx.x;
  int i0 = blockIdx.x*64, d0 = blockIdx.y*64;
  int cx = t&15, ry = t>>4;
  float ca0=0.f,ca1=0.f,ca2=0.f,ca3=0.f;
  #pragma unroll
  for(int rr=0;rr<4;rr++){
    int row = rr*16 + ry;
    f32x4 fv = *(const f32x4*)&F[(size_t)(i0+row)*DD + d0 + cx*4];
    us4 u; u[0]=f2bf(fv[0]); u[1]=f2bf(fv[1]); u[2]=f2bf(fv[2]); u[3]=f2bf(fv[3]);
    *(us4*)&lds[row*68 + cx*4] = u;
    *(us4*)&Fb[(size_t)(i0+row)*DD + d0 + cx*4] = u;
    ca0+=fv[0]; ca1+=fv[1]; ca2+=fv[2]; ca3+=fv[3];
  }
  {
    f32x4 cv; cv[0]=ca0; cv[1]=ca1; cv[2]=ca2; cv[3]=ca3;
    *(f32x4*)&gq[ry*64 + cx*4] = cv;
  }
  __syncthreads();
  // transposed write: FbT[d][i]
  #pragma unroll
  for(int rr=0;rr<4;rr++){
    int d = rr*16 + ry;
    us4 u;
    #pragma unroll
    for(int q=0;q<4;q++) u[q] = lds[(cx*4+q)*68 + d];
    *(us4*)&FbT[(size_t)(d0+d)*NN + i0 + cx*4] = u;
  }
  __syncthreads();
  if(t<64){
    float s=0.f;
    #pragma unroll
    for(int j=0;j<16;j++) s += gq[j*64+t];
    gpart[blockIdx.x*DD + d0 + t] = s;
  }
}

// ---- K2: g[d] = sum over 128 partial groups; 8 blocks x 256 thr, 4-way LDS reduce
__global__ __launch_bounds__(256) void k_gred(const float* __restrict__ gpart,
                                              float* __restrict__ g){
  __shared__ float rs[4][64];
  int t = threadIdx.x;
  int d = blockIdx.x*64 + (t&63);
  int q = t>>6;
  float s = 0.f;
  #pragma unroll
  for(int j=0;j<32;j++) s += gpart[(size_t)(q*32+j)*DD + d];
  rs[q][t&63] = s;
  __syncthreads();
  if(q==0) g[d] = rs[0][t&63]+rs[1][t&63]+rs[2][t&63]+rs[3][t&63];
}

// ---- K4: softmax + transpose: logits [8192][1000] -> PbT bf16 [1024][8192]
//      LDS layout [row-pair][c] (uint), conflict-free writes AND reads.
__global__ __launch_bounds__(256) void k_softmaxT(const float* __restrict__ L,
                                                  unsigned short* __restrict__ PbT){
  __shared__ unsigned int lt[8][1028];   // pad 4 words per row
  int t = threadIdx.x, l = t&63, w = t>>6;
  int i0 = blockIdx.x*16;
  #pragma unroll
  for(int q=0;q<4;q++){
    int rr = w*4 + q;
    int row = i0 + rr;
    const float* lr = L + (size_t)row*CC;
    float v[16]; float mx = -1e30f;
    #pragma unroll
    for(int k=0;k<16;k++){ int c = l + 64*k; v[k] = (c<CC)? lr[c] : -1e30f; mx = fmaxf(mx,v[k]); }
    mx = waveRedMax(mx);
    float s = 0.f;
    #pragma unroll
    for(int k=0;k<16;k++){ v[k] = expf(v[k]-mx); s += v[k]; }
    s = waveRedSum(s);
    float inv = 1.0f/s;
    #pragma unroll
    for(int k=0;k<16;k++){
      int c = l + 64*k;
      float p = v[k]*inv + 1e-8f;
      unsigned short h = (c<CC)? f2bf(p) : (unsigned short)0;
      *((unsigned short*)&lt[rr>>1][c] + (rr&1)) = h;
    }
  }
  __syncthreads();
  #pragma unroll
  for(int k=0;k<4;k++){
    int c = t + 256*k;
    ui4 a, b;
    #pragma unroll
    for(int j=0;j<4;j++){ a[j] = lt[j][c]; b[j] = lt[j+4][c]; }
    *(ui4*)&PbT[(size_t)c*NN + i0]     = a;
    *(ui4*)&PbT[(size_t)c*NN + i0 + 8] = b;
  }
}

// ---- K5: GEMM1: Tpb[z][c][d] = bf16( sum_{k in chunk z} PbT[c][k]*FbT[d][k] )
//      split-K=16 into PRIVATE bf16 partial buffers (no atomics), plain stores.
__global__ __launch_bounds__(256,2) void k_gemm1(const unsigned short* __restrict__ A,  // PbT [1024][8192]
                                                 const unsigned short* __restrict__ B,  // FbT [512][8192]
                                                 unsigned short* __restrict__ Tpb){
  __shared__ unsigned short Al[128*64];
  __shared__ unsigned short Bl[128*64];
  int t = threadIdx.x, l = t&63, w = t>>6;
  int m0 = blockIdx.x*128, n0 = blockIdx.y*128;
  int k0 = blockIdx.z*512;
  int wm = w>>1, wn = w&1;
  f32x4 acc[4][4] = {};
  int srow = w*32 + (l>>3);
  int scl  = (l&7) ^ (srow&7);                 // pre-swizzled source chunk
  const unsigned short* Ab = A + (size_t)(m0 + srow)*NN + k0 + scl*8;
  const unsigned short* Bb = B + (size_t)(n0 + srow)*NN + k0 + scl*8;
  unsigned short* AlB = Al + (w*32)*64;
  unsigned short* BlB = Bl + (w*32)*64;

  for(int kt=0; kt<512; kt+=64){
    __syncthreads();
    #pragma unroll
    for(int q=0;q<4;q++){
      gload_lds16(Ab + (size_t)q*8*NN + kt, AlB + q*8*64);
      gload_lds16(Bb + (size_t)q*8*NN + kt, BlB + q*8*64);
    }
    asm volatile("s_waitcnt vmcnt(0)" ::: "memory");
    __syncthreads();
    #pragma unroll
    for(int ks=0;ks<2;ks++){
      short8 af[4], bf[4];
      #pragma unroll
      for(int mi=0;mi<4;mi++){
        int r = wm*64 + mi*16 + (l&15);
        int ch = ((ks<<2) + (l>>4)) ^ (r&7);
        af[mi] = *(const short8*)&Al[r*64 + ch*8];
      }
      #pragma unroll
      for(int ni=0;ni<4;ni++){
        int r = wn*64 + ni*16 + (l&15);
        int ch = ((ks<<2) + (l>>4)) ^ (r&7);
        bf[ni] = *(const short8*)&Bl[r*64 + ch*8];
      }
      #pragma unroll
      for(int mi=0;mi<4;mi++)
        #pragma unroll
        for(int ni=0;ni<4;ni++)
          acc[mi][ni] = __builtin_amdgcn_mfma_f32_16x16x32_bf16(af[mi], bf[ni], acc[mi][ni], 0,0,0);
    }
  }
  unsigned short* Tz = Tpb + (size_t)blockIdx.z*CP*DD;
  int rbase = (l>>4)*4;
  #pragma unroll
  for(int mi=0;mi<4;mi++){
    int c = m0 + wm*64 + mi*16 + rbase;
    #pragma unroll
    for(int ni=0;ni<4;ni++){
      int d = n0 + wn*64 + ni*16 + (l&15);
      #pragma unroll
      for(int j=0;j<4;j++)
        Tz[(size_t)(c+j)*DD + d] = f2bf(acc[mi][ni][j]);
    }
  }
}

// ---- K6: reduce 16 bf16 partials -> Ttb bf16 (phase 1) AND invr (phase 2)
__global__ __launch_bounds__(256) void k_redT(const unsigned short* __restrict__ Tpb,
                                              const unsigned short* __restrict__ Fb,
                                              const float* __restrict__ g,
                                              unsigned short* __restrict__ Ttb,
                                              float* __restrict__ invr){
  int t = threadIdx.x;
  // phase 1: Ttb = bf16(sum_z Tpb[z]) ; 256 blocks x 256 threads x 8 elems = CP*DD
  size_t i = ((size_t)blockIdx.x*256 + (size_t)t)*8;
  f32x4 s0 = {0.f,0.f,0.f,0.f}, s1 = {0.f,0.f,0.f,0.f};
  #pragma unroll
  for(int z=0;z<16;z++){
    us8 v = *(const us8*)&Tpb[(size_t)z*CP*DD + i];
    s0[0]+=bf2f(v[0]); s0[1]+=bf2f(v[1]); s0[2]+=bf2f(v[2]); s0[3]+=bf2f(v[3]);
    s1[0]+=bf2f(v[4]); s1[1]+=bf2f(v[5]); s1[2]+=bf2f(v[6]); s1[3]+=bf2f(v[7]);
  }
  us8 u;
  u[0]=f2bf(s0[0]); u[1]=f2bf(s0[1]); u[2]=f2bf(s0[2]); u[3]=f2bf(s0[3]);
  u[4]=f2bf(s1[0]); u[5]=f2bf(s1[1]); u[6]=f2bf(s1[2]); u[7]=f2bf(s1[3]);
  *(us8*)&Ttb[i] = u;
  // phase 2: invr for rows blockIdx.x*32 .. +31 (8 lanes per row)
  int row = blockIdx.x*32 + (t>>3);
  int seg = (t&7)*64;
  const unsigned short* fr = Fb + (size_t)row*DD + seg;
  const float* gr = g + seg;
  float s = 0.f;
  #pragma unroll
  for(int j=0;j<8;j++){
    us8 f8 = *(const us8*)&fr[j*8];
    f32x4 ga = *(const f32x4*)&gr[j*8];
    f32x4 gb = *(const f32x4*)&gr[j*8+4];
    s += bf2f(f8[0])*ga[0]+bf2f(f8[1])*ga[1]+bf2f(f8[2])*ga[2]+bf2f(f8[3])*ga[3]
       + bf2f(f8[4])*gb[0]+bf2f(f8[5])*gb[1]+bf2f(f8[6])*gb[2]+bf2f(f8[7])*gb[3];
  }
  s += __shfl_xor(s,1,64); s += __shfl_xor(s,2,64); s += __shfl_xor(s,4,64);
  if((t&7)==0) invr[row] = 1.0f/(s - 1.0f);
}

// ---- K7: GEMM2: M[i][c] = sum_d Fb[i][d]*Ttb[c][d]; fused KL epilogue
//      grid (8 c-blocks, 64 i-blocks): x-fastest dispatch keeps Fb slice L2-hot
__global__ __launch_bounds__(256,2) void k_gemm2(const unsigned short* __restrict__ Fb,   // [8192][512]
                                                 const unsigned short* __restrict__ Bt,   // Ttb [1024][512]
                                                 const unsigned short* __restrict__ PbT,  // [1024][8192]
                                                 const float* __restrict__ invr,
                                                 float* __restrict__ partials){
  __shared__ unsigned short Al[128*64];
  __shared__ unsigned short Bl[128*64];
  __shared__ float red[4];
  int t = threadIdx.x, l = t&63, w = t>>6;
  int m0 = blockIdx.y*128, n0 = blockIdx.x*128;
  int wm = w>>1, wn = w&1;
  f32x4 acc[4][4] = {};
  int srow = w*32 + (l>>3);
  int scl  = (l&7) ^ (srow&7);
  const unsigned short* Ab = Fb + (size_t)(m0 + srow)*DD + scl*8;
  const unsigned short* Bb = Bt + (size_t)(n0 + srow)*DD + scl*8;
  unsigned short* AlB = Al + (w*32)*64;
  unsigned short* BlB = Bl + (w*32)*64;

  for(int kt=0; kt<512; kt+=64){
    __syncthreads();
    #pragma unroll
    for(int q=0;q<4;q++){
      gload_lds16(Ab + (size_t)q*8*DD + kt, AlB + q*8*64);
      gload_lds16(Bb + (size_t)q*8*DD + kt, BlB + q*8*64);
    }
    asm volatile("s_waitcnt vmcnt(0)" ::: "memory");
    __syncthreads();
    #pragma unroll
    for(int ks=0;ks<2;ks++){
      short8 af[4], bf[4];
      #pragma unroll
      for(int mi=0;mi<4;mi++){
        int r = wm*64 + mi*16 + (l&15);
        int ch = ((ks<<2) + (l>>4)) ^ (r&7);
        af[mi] = *(const short8*)&Al[r*64 + ch*8];
      }
      #pragma unroll
      for(int ni=0;ni<4;ni++){
        int r = wn*64 + ni*16 + (l&15);
        int ch = ((ks<<2) + (l>>4)) ^ (r&7);
        bf[ni] = *(const short8*)&Bl[r*64 + ch*8];
      }
      #pragma unroll
      for(int mi=0;mi<4;mi++)
        #pragma unroll
        for(int ni=0;ni<4;ni++)
          acc[mi][ni] = __builtin_amdgcn_mfma_f32_16x16x32_bf16(af[mi], bf[ni], acc[mi][ni], 0,0,0);
    }
  }
  // KL epilogue
  float kl = 0.f;
  int rbase = (l>>4)*4;
  #pragma unroll
  for(int mi=0;mi<4;mi++){
    int i_base = m0 + wm*64 + mi*16 + rbase;
    f32x4 ir4 = *(const f32x4*)&invr[i_base];
    #pragma unroll
    for(int ni=0;ni<4;ni++){
      int c = n0 + wn*64 + ni*16 + (l&15);
      if(c < CC){
        us4 p4 = *(const us4*)&PbT[(size_t)c*NN + i_base];
        #pragma unroll
        for(int j=0;j<4;j++){
          float p = bf2f(p4[j]);
          float ws = (acc[mi][ni][j] - p) * ir4[j];
          kl += ws * logf(ws/p);
        }
      }
    }
  }
  kl = waveRedSum(kl);
  if(l==0) red[w]=kl;
  __syncthreads();
  if(t==0) partials[blockIdx.y*8 + blockIdx.x] = red[0]+red[1]+red[2]+red[3];
}

// ---- K8: finalize
__global__ __launch_bounds__(64) void k_finalize(const float* __restrict__ partials,
                                                 float* __restrict__ out){
  int l = threadIdx.x;
  double s = 0.0;
  for(int j=l; j<512; j+=64) s += (double)partials[j];
  #pragma unroll
  for(int o=32;o;o>>=1) s += __shfl_xor(s,o,64);
  if(l==0) out[0] = (float)(s / (double)NN);
}

extern "C" void kernel_launch(void* const* d_in, const int* in_sizes, int n_in,
                              void* d_out, int out_size, void* d_ws, size_t ws_size,
                              hipStream_t stream){
  const float* F = (const float*)d_in[0];   // [8192][512]
  const float* L = (const float*)d_in[1];   // [8192][1000]
  float* out = (float*)d_out;

  unsigned char* w8 = (unsigned char*)d_ws;
  unsigned short* FbT = (unsigned short*)w8;                   // 512*8192*2      = 8 MB
  unsigned short* PbT = (unsigned short*)(w8 + (8u<<20));      // 1024*8192*2     = 16 MB
  unsigned short* Tpb = (unsigned short*)(w8 + (24u<<20));     // 16*1024*512*2   = 16 MB
  unsigned short* Ttb = (unsigned short*)(w8 + (40u<<20));     // 1024*512*2      = 1 MB
  unsigned short* Fb  = (unsigned short*)(w8 + (41u<<20));     // 8192*512*2      = 8 MB
  float* gpart        = (float*)(w8 + (49u<<20));              // 128*512*4       = 256 KB
  float* g            = (float*)(w8 + (49u<<20) + 262144);     // 512*4
  float* invr         = (float*)(w8 + (49u<<20) + 264192);     // 8192*4
  float* partials     = (float*)(w8 + (49u<<20) + 296960);     // 512*4

  hipLaunchKernelGGL(k_castF,    dim3(128,8),  dim3(256), 0, stream, F, FbT, Fb, gpart);
  hipLaunchKernelGGL(k_gred,     dim3(8),      dim3(256), 0, stream, gpart, g);
  hipLaunchKernelGGL(k_softmaxT, dim3(512),    dim3(256), 0, stream, L, PbT);
  hipLaunchKernelGGL(k_gemm1,    dim3(8,4,16), dim3(256), 0, stream, PbT, FbT, Tpb);
  hipLaunchKernelGGL(k_redT,     dim3(256),    dim3(256), 0, stream, Tpb, Fb, g, Ttb, invr);
  hipLaunchKernelGGL(k_gemm2,    dim3(8,64),   dim3(256), 0, stream, Fb, Ttb, PbT, invr, partials);
  hipLaunchKernelGGL(k_finalize, dim3(1),      dim3(64),  0, stream, partials, out);
}

// Round 7
// 73.744 us; speedup vs baseline: 8.4992x; 1.0525x over previous
//
#include <hip/hip_runtime.h>
#include <math.h>

#define NN 8192
#define DD 512
#define CC 1000
#define CP 1024   // padded C

typedef __attribute__((ext_vector_type(8))) short short8;     // bf16x8 MFMA frag
typedef __attribute__((ext_vector_type(4))) float f32x4;
typedef __attribute__((ext_vector_type(4))) unsigned short us4;
typedef __attribute__((ext_vector_type(8))) unsigned short us8;
typedef __attribute__((ext_vector_type(4))) unsigned int ui4;

__device__ __forceinline__ float bf2f(unsigned short u){
  union{unsigned int i; float f;} v; v.i = ((unsigned int)u)<<16; return v.f;
}
__device__ __forceinline__ unsigned short f2bf(float f){
  union{float f; unsigned int i;} v; v.f = f;
  unsigned int r = v.i + 0x7FFF + ((v.i>>16)&1);   // RNE
  return (unsigned short)(r>>16);
}
__device__ __forceinline__ float waveRedSum(float v){
  #pragma unroll
  for(int o=32;o;o>>=1) v += __shfl_xor(v,o,64);
  return v;
}
__device__ __forceinline__ float waveRedMax(float v){
  #pragma unroll
  for(int o=32;o;o>>=1) v = fmaxf(v,__shfl_xor(v,o,64));
  return v;
}
__device__ __forceinline__ void gload_lds16(const void* g, void* l){
  __builtin_amdgcn_global_load_lds((const __attribute__((address_space(1))) void*)g,
                                   (__attribute__((address_space(3))) void*)l, 16, 0, 0);
}

// ---- K1: merged prep. Blocks interleaved 2 castF : 1 softmaxT (512 groups of 3).
//  castF (1024 blocks): F fp32 -> FbT bf16 [512][8192] + Fb bf16 [8192][512] + gpart
//  softmaxT (512 blocks): logits -> PbT bf16 [1024][8192] (transposed, +1e-8)
__global__ __launch_bounds__(256) void k_prep(const float* __restrict__ F,
                                              const float* __restrict__ L,
                                              unsigned short* __restrict__ FbT,
                                              unsigned short* __restrict__ Fb,
                                              float* __restrict__ gpart,
                                              unsigned short* __restrict__ PbT){
  __shared__ __align__(16) char smem[8*1028*4];   // 32.9 KB union
  int bid = blockIdx.x;
  int grp = bid/3, r = bid - grp*3;
  int t = threadIdx.x;

  if(r < 2){
    // ---------- castF path, block index cb in [0,1024) ----------
    int cb = grp*2 + r;
    unsigned short* lds = (unsigned short*)smem;           // [64*68]
    float* gq = (float*)(smem + 64*68*2);                  // [16*64]
    int i0 = (cb & 127)*64, d0 = (cb >> 7)*64;
    int cx = t&15, ry = t>>4;
    float ca0=0.f,ca1=0.f,ca2=0.f,ca3=0.f;
    #pragma unroll
    for(int rr=0;rr<4;rr++){
      int row = rr*16 + ry;
      f32x4 fv = *(const f32x4*)&F[(size_t)(i0+row)*DD + d0 + cx*4];
      us4 u; u[0]=f2bf(fv[0]); u[1]=f2bf(fv[1]); u[2]=f2bf(fv[2]); u[3]=f2bf(fv[3]);
      *(us4*)&lds[row*68 + cx*4] = u;
      *(us4*)&Fb[(size_t)(i0+row)*DD + d0 + cx*4] = u;
      ca0+=fv[0]; ca1+=fv[1]; ca2+=fv[2]; ca3+=fv[3];
    }
    {
      f32x4 cv; cv[0]=ca0; cv[1]=ca1; cv[2]=ca2; cv[3]=ca3;
      *(f32x4*)&gq[ry*64 + cx*4] = cv;
    }
    __syncthreads();
    #pragma unroll
    for(int rr=0;rr<4;rr++){
      int d = rr*16 + ry;
      us4 u;
      #pragma unroll
      for(int q=0;q<4;q++) u[q] = lds[(cx*4+q)*68 + d];
      *(us4*)&FbT[(size_t)(d0+d)*NN + i0 + cx*4] = u;
    }
    __syncthreads();
    if(t<64){
      float s=0.f;
      #pragma unroll
      for(int j=0;j<16;j++) s += gq[j*64+t];
      gpart[cb&127 ? (cb&127)*DD + d0 + t : d0 + t] = s;   // = (cb&127)*DD + d0 + t
    }
  } else {
    // ---------- softmaxT path, block index sb in [0,512) ----------
    int sb = grp;
    unsigned int (*lt)[1028] = (unsigned int(*)[1028])smem;
    int l = t&63, w = t>>6;
    int i0 = sb*16;
    #pragma unroll
    for(int q=0;q<4;q++){
      int rr = w*4 + q;
      int row = i0 + rr;
      const float* lr = L + (size_t)row*CC;
      float v[16]; float mx = -1e30f;
      #pragma unroll
      for(int k=0;k<16;k++){ int c = l + 64*k; v[k] = (c<CC)? lr[c] : -1e30f; mx = fmaxf(mx,v[k]); }
      mx = waveRedMax(mx);
      float s = 0.f;
      #pragma unroll
      for(int k=0;k<16;k++){ v[k] = __expf(v[k]-mx); s += v[k]; }
      s = waveRedSum(s);
      float inv = 1.0f/s;
      #pragma unroll
      for(int k=0;k<16;k++){
        int c = l + 64*k;
        float p = v[k]*inv + 1e-8f;
        unsigned short h = (c<CC)? f2bf(p) : (unsigned short)0;
        *((unsigned short*)&lt[rr>>1][c] + (rr&1)) = h;
      }
    }
    __syncthreads();
    #pragma unroll
    for(int k=0;k<4;k++){
      int c = t + 256*k;
      ui4 a, b;
      #pragma unroll
      for(int j=0;j<4;j++){ a[j] = lt[j][c]; b[j] = lt[j+4][c]; }
      *(ui4*)&PbT[(size_t)c*NN + i0]     = a;
      *(ui4*)&PbT[(size_t)c*NN + i0 + 8] = b;
    }
  }
}

// ---- K2: GEMM1 (blocks 0..511) + gred (blocks 512..519)
//  gemm1: Tpb[z][c][d] = bf16( sum_{k in chunk z} PbT[c][k]*FbT[d][k] ), private partials
//  gred:  g[d] = sum over 128 gpart groups
__global__ __launch_bounds__(256,2) void k_gemm1(const unsigned short* __restrict__ A,  // PbT [1024][8192]
                                                 const unsigned short* __restrict__ B,  // FbT [512][8192]
                                                 unsigned short* __restrict__ Tpb,
                                                 const float* __restrict__ gpart,
                                                 float* __restrict__ g){
  __shared__ unsigned short Al[128*64];
  __shared__ unsigned short Bl[128*64];
  __shared__ float rs[4][64];
  int bid = blockIdx.x;
  int t = threadIdx.x;
  if(bid >= 512){
    int gb = bid - 512;
    int d = gb*64 + (t&63);
    int q = t>>6;
    float s = 0.f;
    #pragma unroll
    for(int j=0;j<32;j++) s += gpart[(size_t)(q*32+j)*DD + d];
    rs[q][t&63] = s;
    __syncthreads();
    if(q==0) g[d] = rs[0][t&63]+rs[1][t&63]+rs[2][t&63]+rs[3][t&63];
    return;
  }
  int l = t&63, w = t>>6;
  int bx = bid & 7, byz = bid >> 3;
  int by = byz & 3, bz = byz >> 2;
  int m0 = bx*128, n0 = by*128;
  int k0 = bz*512;
  int wm = w>>1, wn = w&1;
  f32x4 acc[4][4] = {};
  int srow = w*32 + (l>>3);
  int scl  = (l&7) ^ (srow&7);                 // pre-swizzled source chunk
  const unsigned short* Ab = A + (size_t)(m0 + srow)*NN + k0 + scl*8;
  const unsigned short* Bb = B + (size_t)(n0 + srow)*NN + k0 + scl*8;
  unsigned short* AlB = Al + (w*32)*64;
  unsigned short* BlB = Bl + (w*32)*64;

  for(int kt=0; kt<512; kt+=64){
    __syncthreads();
    #pragma unroll
    for(int q=0;q<4;q++){
      gload_lds16(Ab + (size_t)q*8*NN + kt, AlB + q*8*64);
      gload_lds16(Bb + (size_t)q*8*NN + kt, BlB + q*8*64);
    }
    asm volatile("s_waitcnt vmcnt(0)" ::: "memory");
    __syncthreads();
    #pragma unroll
    for(int ks=0;ks<2;ks++){
      short8 af[4], bf[4];
      #pragma unroll
      for(int mi=0;mi<4;mi++){
        int rr = wm*64 + mi*16 + (l&15);
        int ch = ((ks<<2) + (l>>4)) ^ (rr&7);
        af[mi] = *(const short8*)&Al[rr*64 + ch*8];
      }
      #pragma unroll
      for(int ni=0;ni<4;ni++){
        int rr = wn*64 + ni*16 + (l&15);
        int ch = ((ks<<2) + (l>>4)) ^ (rr&7);
        bf[ni] = *(const short8*)&Bl[rr*64 + ch*8];
      }
      #pragma unroll
      for(int mi=0;mi<4;mi++)
        #pragma unroll
        for(int ni=0;ni<4;ni++)
          acc[mi][ni] = __builtin_amdgcn_mfma_f32_16x16x32_bf16(af[mi], bf[ni], acc[mi][ni], 0,0,0);
    }
  }
  unsigned short* Tz = Tpb + (size_t)bz*CP*DD;
  int rbase = (l>>4)*4;
  #pragma unroll
  for(int mi=0;mi<4;mi++){
    int c = m0 + wm*64 + mi*16 + rbase;
    #pragma unroll
    for(int ni=0;ni<4;ni++){
      int d = n0 + wn*64 + ni*16 + (l&15);
      #pragma unroll
      for(int j=0;j<4;j++)
        Tz[(size_t)(c+j)*DD + d] = f2bf(acc[mi][ni][j]);
    }
  }
}

// ---- K3: reduce 16 bf16 partials -> Ttb bf16 (phase 1) AND invr (phase 2)
__global__ __launch_bounds__(256) void k_redT(const unsigned short* __restrict__ Tpb,
                                              const unsigned short* __restrict__ Fb,
                                              const float* __restrict__ g,
                                              unsigned short* __restrict__ Ttb,
                                              float* __restrict__ invr){
  int t = threadIdx.x;
  size_t i = ((size_t)blockIdx.x*256 + (size_t)t)*8;
  f32x4 s0 = {0.f,0.f,0.f,0.f}, s1 = {0.f,0.f,0.f,0.f};
  #pragma unroll
  for(int z=0;z<16;z++){
    us8 v = *(const us8*)&Tpb[(size_t)z*CP*DD + i];
    s0[0]+=bf2f(v[0]); s0[1]+=bf2f(v[1]); s0[2]+=bf2f(v[2]); s0[3]+=bf2f(v[3]);
    s1[0]+=bf2f(v[4]); s1[1]+=bf2f(v[5]); s1[2]+=bf2f(v[6]); s1[3]+=bf2f(v[7]);
  }
  us8 u;
  u[0]=f2bf(s0[0]); u[1]=f2bf(s0[1]); u[2]=f2bf(s0[2]); u[3]=f2bf(s0[3]);
  u[4]=f2bf(s1[0]); u[5]=f2bf(s1[1]); u[6]=f2bf(s1[2]); u[7]=f2bf(s1[3]);
  *(us8*)&Ttb[i] = u;
  // phase 2: invr for rows blockIdx.x*32 .. +31 (8 lanes per row)
  int row = blockIdx.x*32 + (t>>3);
  int seg = (t&7)*64;
  const unsigned short* fr = Fb + (size_t)row*DD + seg;
  const float* gr = g + seg;
  float s = 0.f;
  #pragma unroll
  for(int j=0;j<8;j++){
    us8 f8 = *(const us8*)&fr[j*8];
    f32x4 ga = *(const f32x4*)&gr[j*8];
    f32x4 gb = *(const f32x4*)&gr[j*8+4];
    s += bf2f(f8[0])*ga[0]+bf2f(f8[1])*ga[1]+bf2f(f8[2])*ga[2]+bf2f(f8[3])*ga[3]
       + bf2f(f8[4])*gb[0]+bf2f(f8[5])*gb[1]+bf2f(f8[6])*gb[2]+bf2f(f8[7])*gb[3];
  }
  s += __shfl_xor(s,1,64); s += __shfl_xor(s,2,64); s += __shfl_xor(s,4,64);
  if((t&7)==0) invr[row] = 1.0f/(s - 1.0f);
}

// ---- K4: GEMM2: M[i][c] = sum_d Fb[i][d]*Ttb[c][d]; fused KL epilogue (fast log)
__global__ __launch_bounds__(256,2) void k_gemm2(const unsigned short* __restrict__ Fb,   // [8192][512]
                                                 const unsigned short* __restrict__ Bt,   // Ttb [1024][512]
                                                 const unsigned short* __restrict__ PbT,  // [1024][8192]
                                                 const float* __restrict__ invr,
                                                 float* __restrict__ partials){
  __shared__ unsigned short Al[128*64];
  __shared__ unsigned short Bl[128*64];
  __shared__ float red[4];
  int t = threadIdx.x, l = t&63, w = t>>6;
  int m0 = blockIdx.y*128, n0 = blockIdx.x*128;
  int wm = w>>1, wn = w&1;
  f32x4 acc[4][4] = {};
  int srow = w*32 + (l>>3);
  int scl  = (l&7) ^ (srow&7);
  const unsigned short* Ab = Fb + (size_t)(m0 + srow)*DD + scl*8;
  const unsigned short* Bb = Bt + (size_t)(n0 + srow)*DD + scl*8;
  unsigned short* AlB = Al + (w*32)*64;
  unsigned short* BlB = Bl + (w*32)*64;

  for(int kt=0; kt<512; kt+=64){
    __syncthreads();
    #pragma unroll
    for(int q=0;q<4;q++){
      gload_lds16(Ab + (size_t)q*8*DD + kt, AlB + q*8*64);
      gload_lds16(Bb + (size_t)q*8*DD + kt, BlB + q*8*64);
    }
    asm volatile("s_waitcnt vmcnt(0)" ::: "memory");
    __syncthreads();
    #pragma unroll
    for(int ks=0;ks<2;ks++){
      short8 af[4], bf[4];
      #pragma unroll
      for(int mi=0;mi<4;mi++){
        int rr = wm*64 + mi*16 + (l&15);
        int ch = ((ks<<2) + (l>>4)) ^ (rr&7);
        af[mi] = *(const short8*)&Al[rr*64 + ch*8];
      }
      #pragma unroll
      for(int ni=0;ni<4;ni++){
        int rr = wn*64 + ni*16 + (l&15);
        int ch = ((ks<<2) + (l>>4)) ^ (rr&7);
        bf[ni] = *(const short8*)&Bl[rr*64 + ch*8];
      }
      #pragma unroll
      for(int mi=0;mi<4;mi++)
        #pragma unroll
        for(int ni=0;ni<4;ni++)
          acc[mi][ni] = __builtin_amdgcn_mfma_f32_16x16x32_bf16(af[mi], bf[ni], acc[mi][ni], 0,0,0);
    }
  }
  // KL epilogue (fast log: ws*log(ws/p) = ws*(__logf(ws)-__logf(p)))
  float kl = 0.f;
  int rbase = (l>>4)*4;
  #pragma unroll
  for(int mi=0;mi<4;mi++){
    int i_base = m0 + wm*64 + mi*16 + rbase;
    f32x4 ir4 = *(const f32x4*)&invr[i_base];
    #pragma unroll
    for(int ni=0;ni<4;ni++){
      int c = n0 + wn*64 + ni*16 + (l&15);
      if(c < CC){
        us4 p4 = *(const us4*)&PbT[(size_t)c*NN + i_base];
        #pragma unroll
        for(int j=0;j<4;j++){
          float p = bf2f(p4[j]);
          float ws = (acc[mi][ni][j] - p) * ir4[j];
          kl += ws * (__logf(ws) - __logf(p));
        }
      }
    }
  }
  kl = waveRedSum(kl);
  if(l==0) red[w]=kl;
  __syncthreads();
  if(t==0) partials[blockIdx.y*8 + blockIdx.x] = red[0]+red[1]+red[2]+red[3];
}

// ---- K5: finalize
__global__ __launch_bounds__(64) void k_finalize(const float* __restrict__ partials,
                                                 float* __restrict__ out){
  int l = threadIdx.x;
  double s = 0.0;
  for(int j=l; j<512; j+=64) s += (double)partials[j];
  #pragma unroll
  for(int o=32;o;o>>=1) s += __shfl_xor(s,o,64);
  if(l==0) out[0] = (float)(s / (double)NN);
}

extern "C" void kernel_launch(void* const* d_in, const int* in_sizes, int n_in,
                              void* d_out, int out_size, void* d_ws, size_t ws_size,
                              hipStream_t stream){
  const float* F = (const float*)d_in[0];   // [8192][512]
  const float* L = (const float*)d_in[1];   // [8192][1000]
  float* out = (float*)d_out;

  unsigned char* w8 = (unsigned char*)d_ws;
  unsigned short* FbT = (unsigned short*)w8;                   // 512*8192*2      = 8 MB
  unsigned short* PbT = (unsigned short*)(w8 + (8u<<20));      // 1024*8192*2     = 16 MB
  unsigned short* Tpb = (unsigned short*)(w8 + (24u<<20));     // 16*1024*512*2   = 16 MB
  unsigned short* Ttb = (unsigned short*)(w8 + (40u<<20));     // 1024*512*2      = 1 MB
  unsigned short* Fb  = (unsigned short*)(w8 + (41u<<20));     // 8192*512*2      = 8 MB
  float* gpart        = (float*)(w8 + (49u<<20));              // 128*512*4       = 256 KB
  float* g            = (float*)(w8 + (49u<<20) + 262144);     // 512*4
  float* invr         = (float*)(w8 + (49u<<20) + 264192);     // 8192*4
  float* partials     = (float*)(w8 + (49u<<20) + 296960);     // 512*4

  hipLaunchKernelGGL(k_prep,     dim3(1536),   dim3(256), 0, stream, F, L, FbT, Fb, gpart, PbT);
  hipLaunchKernelGGL(k_gemm1,    dim3(520),    dim3(256), 0, stream, PbT, FbT, Tpb, gpart, g);
  hipLaunchKernelGGL(k_redT,     dim3(256),    dim3(256), 0, stream, Tpb, Fb, g, Ttb, invr);
  hipLaunchKernelGGL(k_gemm2,    dim3(8,64),   dim3(256), 0, stream, Fb, Ttb, PbT, invr, partials);
  hipLaunchKernelGGL(k_finalize, dim3(1),      dim3(64),  0, stream, partials, out);
}